// Round 4
// baseline (337.040 us; speedup 1.0000x reference)
//
#include <hip/hip_runtime.h>
#include <stdint.h>

namespace {

constexpr int B = 8;
constexpr int H = 1024;
constexpr int W = 1024;
constexpr int TOPK = 4096;
constexpr int CAND_CAP = 131072;  // per batch
constexpr int SEL_CAP = 16384;    // per batch
constexpr int LIST_CAP = 320;     // per 64x64 tile

// fused-NMS tile: 64x64 interior, radius-12 staged halo.
// Validity chain (3 fused stages): M0 mask valid rows [2,89]/cols [2,86);
// M1 (cumulative after iter1) valid rows [4,87]/cols [4,84); final emission
// valid rows [6,85]/cols [6,82) => interior rows/cols 12..75 fully covered.
constexpr int RROWS = 92;   // staged score rows
constexpr int NG = 22;      // float4 col-groups (88 cols)
constexpr int STR = 88;     // score row stride (floats)
constexpr int MW4 = 4;      // bitpacked mask words per row (96+ bits; word 3 = zero pad)
constexpr int NSTRIP = 11;  // 11 strips x 8 output rows = rows 2..89
constexpr int NUNIT = NG * NSTRIP;  // 242 <= 256

constexpr int RK_CH = 1024;  // rank kernel: keys staged in LDS per chunk

// workspace layout (bytes). No global histogram (round-1/2 lesson: device-scope
// atomics to hot lines bounce between XCDs). Threshold is found hierarchically
// from cand with two 256-bin LDS histograms (2 KiB static LDS — round-3 lesson:
// 128 KiB dynamic LDS + hipFuncSetAttribute in kernel_launch kills the harness).
constexpr size_t OFF_CNT   = 0;                                  // 4 KiB
constexpr size_t OFF_SEL   = 4096;                               // B*SEL_CAP*8 = 1 MiB
constexpr size_t OFF_TOPK  = OFF_SEL + (size_t)B * SEL_CAP * 8;  // 256 KiB
constexpr size_t OFF_CAND  = OFF_TOPK + (size_t)B * TOPK * 8;    // 8 MiB
constexpr size_t MEMSET_BYTES = 4096;  // cnt page only

__device__ __forceinline__ float max5(float a, float b, float c, float d, float e) {
  return fmaxf(fmaxf(fmaxf(a, b), fmaxf(c, d)), e);
}
__device__ __forceinline__ float4 ld4(const float* p) {
  return *reinterpret_cast<const float4*>(p);
}

// One unit: col-group G in [0,22), strip s in [0,11) -> emission rows r0..r0+7
// (r0 = 2+8s). PASS 0: plain local-max -> M0. PASS 1/2: inline dilation of the
// previous mask via a 2-row-lookahead ring (mask rows run 2 ahead of score rows,
// which run 2 ahead of emission). PASS 1 writes cumulative mask M1 = M0|new.
// PASS 2 emits candidates into the LDS list.
template <int PASS>
__device__ __forceinline__ void score_pass(
    int u, int x0, int y0, const float* __restrict__ S,
    const uint32_t* __restrict__ MIN_, uint32_t* __restrict__ MOUT,
    uint64_t* list, uint32_t* cnt_loc, uint64_t* cand, uint32_t* cand_count, int b) {
  const int G = u % NG, s = u / NG;
  const int r0 = 2 + 8 * s;
  const int gx0 = x0 - 12 + 4 * G;
  uint32_t colm = 0;
#pragma unroll
  for (int j = 0; j < 4; ++j)
    if ((unsigned)(gx0 + j) < (unsigned)W) colm |= 1u << j;

  // 16-col mask window starting at p2 = 4G-6 (covers 5-wide OR for 12 score cols)
  const int p2 = 4 * G - 6;
  const int pw2 = (p2 < 0) ? 0 : (p2 >> 5);
  const int psh2 = (p2 < 0) ? 0 : (p2 & 31);
  const int pls2 = (p2 < 0) ? -p2 : 0;

  float4 hw[5], cw[5];
  uint32_t snr[5], mor[5], cnb[5];
  constexpr int NK = (PASS == 0) ? 12 : 16;
#pragma unroll
  for (int k = 0; k < NK; ++k) {
    if (PASS != 0) {
      // mask row mr = r0-4+k; horizontal 5-OR (bit i <-> supp col 4G-4+i) +
      // center nibble (cols 4G..4G+3) for the cumulative mask.
      const int mr = r0 - 4 + k;
      uint32_t morrow = 0, cnib = 0;
      if ((unsigned)mr < (unsigned)RROWS) {
        const uint32_t* srow = MIN_ + mr * MW4;
        uint64_t X = (uint64_t)srow[pw2] | ((uint64_t)srow[pw2 + 1] << 32);
        uint64_t win = pls2 ? (X << pls2) : (X >> psh2);
        uint64_t t5 = win | (win >> 1) | (win >> 2) | (win >> 3) | (win >> 4);
        morrow = (uint32_t)t5 & 0xFFFu;
        cnib = (uint32_t)(win >> 6) & 0xFu;
      }
      mor[k % 5] = morrow;
      cnb[k % 5] = cnib;
    }
    const int ks = (PASS == 0) ? k : k - 4;
    if (ks >= 0) {
      // score row sr = r0-2+ks; its 2D supp = OR of mor ring (mask rows sr-2..sr+2)
      const int sr = r0 - 2 + ks;
      uint32_t supp = 0;
      if (PASS != 0) supp = mor[0] | mor[1] | mor[2] | mor[3] | mor[4];
      const float* rowp = S + sr * STR + 4 * G;
      float4 d = ld4(rowp);
      float4 a = (G > 0) ? ld4(rowp - 4) : d;  // garbage-only cols, safe
      float4 e = (G < NG - 1) ? ld4(rowp + 4) : d;
      if (PASS != 0) {
        if (supp & 0x001u) a.x = 0.f;
        if (supp & 0x002u) a.y = 0.f;
        if (supp & 0x004u) a.z = 0.f;
        if (supp & 0x008u) a.w = 0.f;
        if (supp & 0x010u) d.x = 0.f;
        if (supp & 0x020u) d.y = 0.f;
        if (supp & 0x040u) d.z = 0.f;
        if (supp & 0x080u) d.w = 0.f;
        if (supp & 0x100u) e.x = 0.f;
        if (supp & 0x200u) e.y = 0.f;
        if (supp & 0x400u) e.z = 0.f;
        if (supp & 0x800u) e.w = 0.f;
      }
      float4 hm;
      hm.x = max5(a.z, a.w, d.x, d.y, d.z);
      hm.y = max5(a.w, d.x, d.y, d.z, d.w);
      hm.z = max5(d.x, d.y, d.z, d.w, e.x);
      hm.w = max5(d.y, d.z, d.w, e.x, e.y);
      hw[ks % 5] = hm;
      cw[ks % 5] = d;
      snr[ks % 5] = (supp >> 4) & 0xFu;
      if (ks >= 4) {
        const int rq = r0 - 4 + ks;  // emission row
        const int gy = y0 - 12 + rq;
        float4 vm;
        vm.x = max5(hw[0].x, hw[1].x, hw[2].x, hw[3].x, hw[4].x);
        vm.y = max5(hw[0].y, hw[1].y, hw[2].y, hw[3].y, hw[4].y);
        vm.z = max5(hw[0].z, hw[1].z, hw[2].z, hw[3].z, hw[4].z);
        vm.w = max5(hw[0].w, hw[1].w, hw[2].w, hw[3].w, hw[4].w);
        float4 c = cw[(ks + 3) % 5];  // center (masked for PASS 1/2)
        uint32_t nm = (uint32_t)(c.x == vm.x) | ((uint32_t)(c.y == vm.y) << 1) |
                      ((uint32_t)(c.z == vm.z) << 2) | ((uint32_t)(c.w == vm.w) << 3);
        nm &= ((unsigned)gy < (unsigned)H) ? colm : 0u;
        const int widx = rq * MW4 + (G >> 3);
        const int shift = 4 * (G & 7);
        if (PASS == 0) {
          if (nm) atomicOr(&MOUT[widx], nm << shift);
        } else if (PASS == 1) {
          // cumulative mask after iter1: M0 center nibble | (new & ~supp_center)
          uint32_t fin = cnb[ks % 5] | (nm & ~snr[(ks + 3) % 5]);
          if (fin) atomicOr(&MOUT[widx], fin << shift);
        } else {
          uint32_t fin = cnb[ks % 5] | (nm & ~snr[(ks + 3) % 5]);
          if (fin && G >= 3 && G < 19 && rq >= 12 && rq < 76 && gy >= 2 && gy < H - 2) {
#pragma unroll
            for (int j = 0; j < 4; ++j) {
              if ((fin >> j) & 1u) {
                int gx = gx0 + j;
                if (gx >= 2 && gx < W - 2) {
                  float sval = S[rq * STR + 4 * G + j];  // original (unmasked) score
                  if (sval > 0.0f) {
                    uint32_t bits = __float_as_uint(sval);
                    uint32_t flat = (uint32_t)(gy * W + gx);
                    uint64_t key = ((uint64_t)bits << 32) | (uint64_t)(0xFFFFFFFFu - flat);
                    uint32_t pos = atomicAdd(cnt_loc, 1u);
                    if (pos < (uint32_t)LIST_CAP) {
                      list[pos] = key;
                    } else {  // tie overflow: direct global append (rare)
                      uint32_t pp = atomicAdd(&cand_count[b], 1u);
                      if (pp < (uint32_t)CAND_CAP) cand[(size_t)b * CAND_CAP + pp] = key;
                    }
                  }
                }
              }
            }
          }
        }
      }
    }
  }
}

// ---------------- fused 3-pass NMS + candidate emit ----------------------------------
__global__ void __launch_bounds__(256, 4) k_nms(const float* __restrict__ scores,
                                                uint64_t* __restrict__ cand,
                                                uint32_t* __restrict__ cand_count) {
  __shared__ float S[RROWS * STR];
  __shared__ uint32_t M0s[RROWS * MW4];
  __shared__ uint32_t M1s[RROWS * MW4];
  __shared__ uint64_t list[LIST_CAP];
  __shared__ uint32_t cnt_loc, base_g;
  const int b = blockIdx.z;
  const int x0 = blockIdx.x * 64, y0 = blockIdx.y * 64;
  const int tid = threadIdx.x;
  const float* img = scores + (size_t)b * H * W;
  if (tid == 0) cnt_loc = 0;

  for (int u = tid; u < RROWS * NG; u += 256) {
    int r = u / NG, G = u % NG;
    int gy = y0 - 12 + r, gx = x0 - 12 + 4 * G;
    float4 v;
    if ((unsigned)gy < (unsigned)H && (unsigned)gx < (unsigned)W)
      v = ld4(img + (size_t)gy * W + gx);
    else
      v = make_float4(-INFINITY, -INFINITY, -INFINITY, -INFINITY);
    *reinterpret_cast<float4*>(&S[r * STR + 4 * G]) = v;
  }
  for (int i = tid; i < RROWS * MW4; i += 256) {
    M0s[i] = 0;
    M1s[i] = 0;
  }
  __syncthreads();
  if (tid < NUNIT)
    score_pass<0>(tid, x0, y0, S, nullptr, M0s, nullptr, nullptr, nullptr, nullptr, b);
  __syncthreads();
  if (tid < NUNIT)
    score_pass<1>(tid, x0, y0, S, M0s, M1s, nullptr, nullptr, nullptr, nullptr, b);
  __syncthreads();
  if (tid < NUNIT)
    score_pass<2>(tid, x0, y0, S, M1s, nullptr, list, &cnt_loc, cand, cand_count, b);
  __syncthreads();
  uint32_t nblk = cnt_loc;
  uint32_t nmain = nblk < (uint32_t)LIST_CAP ? nblk : (uint32_t)LIST_CAP;
  if (tid == 0) base_g = atomicAdd(&cand_count[b], nmain);
  __syncthreads();
  uint32_t bg = base_g;
  for (uint32_t i = tid; i < nmain; i += 256) {
    uint32_t pp = bg + i;
    if (pp < (uint32_t)CAND_CAP) cand[(size_t)b * CAND_CAP + pp] = list[i];
  }
}

// ---------------- hierarchical threshold find (2 KiB static LDS) ---------------------
// One block per batch, two passes over that batch's candidates:
//   A: 256-bin exponent histogram (key>>55 = score_bits>>23) -> crossing exponent E.
//   B: 256-bin fine histogram ((key>>47)&0xFF) of keys with exponent E -> bucket j.
// Threshold bucket = (E<<8)|j = score_bits>>15, identical semantics to prior rounds.
// Both passes wave-aggregate via 8-ballot match-any (nearly all candidates share
// exponent 126 -> raw same-address LDS atomics would serialize ~42k deep).
__global__ void __launch_bounds__(1024) k_thresh(const uint64_t* __restrict__ cand,
                                                 const uint32_t* __restrict__ cand_count,
                                                 uint64_t* __restrict__ thr_key) {
  __shared__ uint32_t ehist[256];
  __shared__ uint32_t fhist[256];
  __shared__ int sE;
  __shared__ uint32_t sAbove;
  const int b = blockIdx.x, t = threadIdx.x;
  uint32_t n = cand_count[b];
  if (n > (uint32_t)CAND_CAP) n = CAND_CAP;
  if (t < 256) {
    ehist[t] = 0;
    fhist[t] = 0;
  }
  __syncthreads();
  const uint64_t* cb = cand + (size_t)b * CAND_CAP;
  const int lane = t & 63;
  // pass A: exponent histogram
  for (uint32_t i = t;; i += 1024) {
    bool valid = i < n;
    uint64_t act = __ballot(valid);
    if (!act) break;
    uint32_t bkt = 0;
    if (valid) bkt = (uint32_t)(cb[i] >> 55);  // score_bits>>23 <= 126
    uint64_t peers = act;
#pragma unroll
    for (int bit = 0; bit < 8; ++bit) {
      uint64_t bb = __ballot((bkt >> bit) & 1u);
      peers &= ((bkt >> bit) & 1u) ? bb : ~bb;
    }
    if (valid && (__ffsll((unsigned long long)peers) - 1) == lane)
      atomicAdd(&ehist[bkt], (uint32_t)__popcll((unsigned long long)peers));
  }
  __syncthreads();
  if (t == 0) {
    uint32_t run = 0, above = 0;
    int E = -1;
    for (int e = 255; e >= 0; --e) {
      uint32_t nrun = run + ehist[e];
      if (run < (uint32_t)TOPK && nrun >= (uint32_t)TOPK) {
        E = e;
        above = run;
      }
      run = nrun;
    }
    if (run < (uint32_t)TOPK) E = -1;  // fewer than TOPK candidates: select all
    sE = E;
    sAbove = above;
  }
  __syncthreads();
  const int E = sE;
  if (E < 0) {
    if (t == 0) thr_key[b] = 0ull;
    return;
  }
  // pass B: fine histogram within exponent E
  for (uint32_t i = t;; i += 1024) {
    bool valid = i < n;
    uint64_t act = __ballot(valid);
    if (!act) break;
    uint32_t fb = 0;
    bool has = false;
    if (valid) {
      uint64_t key = cb[i];
      if ((uint32_t)(key >> 55) == (uint32_t)E) {
        fb = (uint32_t)(key >> 47) & 0xFFu;
        has = true;
      }
    }
    uint64_t hact = __ballot(has);
    if (!hact) continue;
    uint64_t peers = hact;
#pragma unroll
    for (int bit = 0; bit < 8; ++bit) {
      uint64_t bb = __ballot((fb >> bit) & 1u);
      peers &= ((fb >> bit) & 1u) ? bb : ~bb;
    }
    if (has && (__ffsll((unsigned long long)peers) - 1) == lane)
      atomicAdd(&fhist[fb], (uint32_t)__popcll((unsigned long long)peers));
  }
  __syncthreads();
  if (t == 0) {
    uint32_t run = sAbove;
    for (int j = 255; j >= 0; --j) {
      run += fhist[j];
      if (run >= (uint32_t)TOPK) {
        thr_key[b] = ((uint64_t)(((uint32_t)E << 8) | (uint32_t)j)) << 47;
        break;
      }
    }
  }
}

// ---------------- compact ------------------------------------------------------------
__global__ void __launch_bounds__(1024) k_compact(const uint64_t* __restrict__ cand,
                                                  const uint32_t* __restrict__ cand_count,
                                                  const uint64_t* __restrict__ thr_key,
                                                  uint64_t* __restrict__ sel,
                                                  uint32_t* __restrict__ sel_count) {
  __shared__ uint64_t list[1024];
  __shared__ uint32_t cnt_loc;
  __shared__ uint32_t base_g;
  const int b = blockIdx.y;
  uint32_t n = cand_count[b];
  if (n > (uint32_t)CAND_CAP) n = CAND_CAP;
  const int tid = threadIdx.x;
  if (tid == 0) cnt_loc = 0;
  __syncthreads();
  uint32_t i = blockIdx.x * 1024 + tid;
  if (i < n) {
    uint64_t key = cand[(size_t)b * CAND_CAP + i];
    if (key >= thr_key[b]) {
      uint32_t pos = atomicAdd(&cnt_loc, 1u);
      list[pos] = key;
    }
  }
  __syncthreads();
  uint32_t nblk = cnt_loc;
  if (tid == 0 && nblk > 0) base_g = atomicAdd(&sel_count[b], nblk);
  __syncthreads();
  if (nblk > 0 && (uint32_t)tid < nblk) {
    uint32_t pp = base_g + tid;
    if (pp < (uint32_t)SEL_CAP) sel[(size_t)b * SEL_CAP + pp] = list[tid];
  }
}

// ---------------- full rank + scatter in one kernel ----------------------------------
// rank[me] = #{keys > me} over all n selected keys (keys distinct => permutation =>
// exact JAX top_k order). Chunks looped in-block; final rank scatters directly.
__global__ void __launch_bounds__(256) k_rank(const uint64_t* __restrict__ sel,
                                              const uint32_t* __restrict__ sel_count,
                                              uint64_t* __restrict__ topk) {
  __shared__ uint64_t keys[RK_CH];  // 8 KiB
  const int b = blockIdx.y;
  uint32_t n = sel_count[b];
  if (n > (uint32_t)SEL_CAP) n = SEL_CAP;
  if (blockIdx.x * 256u >= n) return;  // uniform per block
  const uint64_t* sb = sel + (size_t)b * SEL_CAP;
  const uint32_t me = blockIdx.x * 256u + threadIdx.x;
  const uint64_t kme = (me < n) ? sb[me] : 0ull;
  uint32_t rank = 0;
  for (uint32_t c0 = 0; c0 < n; c0 += RK_CH) {
    uint32_t clen = n - c0;
    if (clen > (uint32_t)RK_CH) clen = RK_CH;
    __syncthreads();
    for (uint32_t i = threadIdx.x; i < clen; i += 256) keys[i] = sb[c0 + i];
    __syncthreads();
    uint32_t i = 0;
    for (; i + 8 <= clen; i += 8) {
      rank += (keys[i] > kme);
      rank += (keys[i + 1] > kme);
      rank += (keys[i + 2] > kme);
      rank += (keys[i + 3] > kme);
      rank += (keys[i + 4] > kme);
      rank += (keys[i + 5] > kme);
      rank += (keys[i + 6] > kme);
      rank += (keys[i + 7] > kme);
    }
    for (; i < clen; ++i) rank += (keys[i] > kme);
  }
  if (me < n && rank < (uint32_t)TOPK) topk[(size_t)b * TOPK + rank] = kme;
}

// ---------------- refinement: 8 lanes per keypoint -----------------------------------
__global__ void __launch_bounds__(256) k_refine(const float* __restrict__ scores,
                                                const uint64_t* __restrict__ topk,
                                                float* __restrict__ out) {
  int gid = blockIdx.x * 256 + threadIdx.x;
  int kp = gid >> 3, ln = gid & 7;
  const int b = kp / TOPK;
  const int k = kp % TOPK;
  uint64_t key = topk[(size_t)b * TOPK + k];
  uint32_t flat = 0xFFFFFFFFu - (uint32_t)(key & 0xFFFFFFFFull);
  if (flat >= (uint32_t)(H * W)) flat = 0;  // pad-key guard
  const int ix = (int)(flat % W);
  const int iy = (int)(flat / W);
  const float* img = scores + (size_t)b * H * W;

  const int nt = (ln == 0) ? 4 : 3;
  float v[4];
  float mymax = -INFINITY;
#pragma unroll
  for (int i = 0; i < 4; ++i) {
    if (i < nt) {
      int t = ln + 8 * i;
      int y = iy + t / 5 - 2, x = ix + t % 5 - 2;
      float val = ((unsigned)x < (unsigned)W && (unsigned)y < (unsigned)H)
                      ? img[(size_t)y * W + x] : 0.0f;
      v[i] = val;
      mymax = fmaxf(mymax, val);
    }
  }
#pragma unroll
  for (int m = 1; m < 8; m <<= 1) mymax = fmaxf(mymax, __shfl_xor(mymax, m));
  float e[4];
  float sum = 0.f, sx = 0.f, sy = 0.f;
#pragma unroll
  for (int i = 0; i < 4; ++i) {
    if (i < nt) {
      int t = ln + 8 * i;
      float ev = expf((v[i] - mymax) / 0.1f);
      e[i] = ev;
      sum += ev;
      sx += ev * (float)(t % 5 - 2);
      sy += ev * (float)(t / 5 - 2);
    }
  }
#pragma unroll
  for (int m = 1; m < 8; m <<= 1) {
    sum += __shfl_xor(sum, m);
    sx += __shfl_xor(sx, m);
    sy += __shfl_xor(sy, m);
  }
  float rx = sx / sum, ry = sy / sum;
  float dsp = 0.f;
#pragma unroll
  for (int i = 0; i < 4; ++i) {
    if (i < nt) {
      int t = ln + 8 * i;
      float dx = ((float)(t % 5 - 2) - rx) * 0.5f;
      float dy = ((float)(t / 5 - 2) - ry) * 0.5f;
      dsp += e[i] * (dx * dx + dy * dy);
    }
  }
#pragma unroll
  for (int m = 1; m < 8; m <<= 1) dsp += __shfl_xor(dsp, m);
  if (ln != 0) return;
  dsp /= sum;
  float kx = ((float)ix + rx) / 1023.0f * 2.0f - 1.0f;
  float ky = ((float)iy + ry) / 1023.0f * 2.0f - 1.0f;
  float px = (kx + 1.0f) * 0.5f * 1023.0f;
  float py = (ky + 1.0f) * 0.5f * 1023.0f;
  float x0f = floorf(px), y0f = floorf(py);
  float wx1 = px - x0f, wx0 = 1.0f - wx1;
  float wy1 = py - y0f, wy0 = 1.0f - wy1;
  int x0 = (int)x0f, y0 = (int)y0f;
  float sc = 0.0f;
  {
    int xs[2] = {x0, x0 + 1};
    int ys[2] = {y0, y0 + 1};
    float wxs[2] = {wx0, wx1};
    float wys[2] = {wy0, wy1};
#pragma unroll
    for (int yy = 0; yy < 2; ++yy)
#pragma unroll
      for (int xx = 0; xx < 2; ++xx) {
        int xi = xs[xx], yi = ys[yy];
        bool valid = (xi >= 0 && xi < W && yi >= 0 && yi < H);
        int xc = min(max(xi, 0), W - 1);
        int yc = min(max(yi, 0), H - 1);
        float vv = valid ? img[(size_t)yc * W + xc] : 0.0f;
        sc += vv * (wxs[xx] * wys[yy]);
      }
  }
  out[((size_t)b * TOPK + k) * 2 + 0] = kx;
  out[((size_t)b * TOPK + k) * 2 + 1] = ky;
  out[(size_t)B * TOPK * 2 + (size_t)b * TOPK + k] = sc;
  out[(size_t)B * TOPK * 3 + (size_t)b * TOPK + k] = dsp;
}

}  // namespace

extern "C" void kernel_launch(void* const* d_in, const int* in_sizes, int n_in,
                              void* d_out, int out_size, void* d_ws, size_t ws_size,
                              hipStream_t stream) {
  const float* scores = (const float*)d_in[0];
  float* out = (float*)d_out;
  char* ws = (char*)d_ws;

  uint32_t* cnt = (uint32_t*)(ws + OFF_CNT);
  uint32_t* cand_count = cnt;                    // [B]
  uint32_t* sel_count  = cnt + 8;                // [B]
  uint64_t* thr_key    = (uint64_t*)(cnt + 16);  // [B]
  uint64_t* sel  = (uint64_t*)(ws + OFF_SEL);
  uint64_t* topk = (uint64_t*)(ws + OFF_TOPK);
  uint64_t* cand = (uint64_t*)(ws + OFF_CAND);

  hipMemsetAsync(ws + OFF_CNT, 0, MEMSET_BYTES, stream);

  k_nms<<<dim3(W / 64, H / 64, B), 256, 0, stream>>>(scores, cand, cand_count);
  k_thresh<<<B, 1024, 0, stream>>>(cand, cand_count, thr_key);
  k_compact<<<dim3(CAND_CAP / 1024, B), 1024, 0, stream>>>(cand, cand_count, thr_key,
                                                           sel, sel_count);
  k_rank<<<dim3(SEL_CAP / 256, B), 256, 0, stream>>>(sel, sel_count, topk);
  k_refine<<<(B * TOPK * 8) / 256, 256, 0, stream>>>(scores, topk, out);
}

// Round 5
// 252.792 us; speedup vs baseline: 1.3333x; 1.3333x over previous
//
#include <hip/hip_runtime.h>
#include <stdint.h>

namespace {

constexpr int B = 8;
constexpr int H = 1024;
constexpr int W = 1024;
constexpr int TOPK = 4096;
constexpr int CAND_CAP = 131072;  // per batch
constexpr int SEL_CAP = 16384;    // per batch
constexpr int LIST_CAP = 320;     // per 64x64 tile
constexpr int NHB = 32;           // hist slice blocks per batch

// fused-NMS tile: 64x64 interior, radius-12 staged halo.
// Validity chain (3 fused stages): M0 mask valid rows [2,89]/cols [2,86);
// M1 (cumulative after iter1) valid rows [4,87]/cols [4,84); final emission
// valid rows [6,85]/cols [6,82) => interior rows/cols 12..75 fully covered.
constexpr int RROWS = 92;   // staged score rows
constexpr int NG = 22;      // float4 col-groups (88 cols)
constexpr int STR = 88;     // score row stride (floats)
constexpr int MW4 = 4;      // bitpacked mask words per row (96+ bits; word 3 = zero pad)
constexpr int NSTRIP = 11;  // 11 strips x 8 output rows = rows 2..89
constexpr int NUNIT = NG * NSTRIP;  // 242 <= 256

constexpr int RK_CH = 1024;  // rank kernel: keys staged in LDS per chunk

// workspace layout (bytes). Threshold = hierarchical exponent/fine-byte histograms,
// grid-parallel (32 blocks/batch) with per-block LDS hists + sparse global merge.
// (round-1/2 lesson: unaggregated hot-line global atomics bounce between XCDs;
//  round-4 lesson: 1-block-per-batch ballot loops waste 97% of the machine.)
constexpr size_t OFF_CNT   = 0;                                  // 4 KiB
constexpr size_t OFF_EH    = 4096;                               // B*256*4 = 8 KiB
constexpr size_t OFF_FH    = OFF_EH + (size_t)B * 256 * 4;       // 8 KiB
constexpr size_t OFF_SEL   = OFF_FH + (size_t)B * 256 * 4;       // B*SEL_CAP*8 = 1 MiB
constexpr size_t OFF_TOPK  = OFF_SEL + (size_t)B * SEL_CAP * 8;  // 256 KiB
constexpr size_t OFF_CAND  = OFF_TOPK + (size_t)B * TOPK * 8;    // 8 MiB
constexpr size_t MEMSET_BYTES = OFF_SEL;  // cnt page + both hist pages

__device__ __forceinline__ float max5(float a, float b, float c, float d, float e) {
  return fmaxf(fmaxf(fmaxf(a, b), fmaxf(c, d)), e);
}
__device__ __forceinline__ float4 ld4(const float* p) {
  return *reinterpret_cast<const float4*>(p);
}

// One unit: col-group G in [0,22), strip s in [0,11) -> emission rows r0..r0+7
// (r0 = 2+8s). PASS 0: plain local-max -> M0. PASS 1/2: inline dilation of the
// previous mask via a 2-row-lookahead ring (mask rows run 2 ahead of score rows,
// which run 2 ahead of emission). PASS 1 writes cumulative mask M1 = M0|new.
// PASS 2 emits candidates into the LDS list.
template <int PASS>
__device__ __forceinline__ void score_pass(
    int u, int x0, int y0, const float* __restrict__ S,
    const uint32_t* __restrict__ MIN_, uint32_t* __restrict__ MOUT,
    uint64_t* list, uint32_t* cnt_loc, uint64_t* cand, uint32_t* cand_count, int b) {
  const int G = u % NG, s = u / NG;
  const int r0 = 2 + 8 * s;
  const int gx0 = x0 - 12 + 4 * G;
  uint32_t colm = 0;
#pragma unroll
  for (int j = 0; j < 4; ++j)
    if ((unsigned)(gx0 + j) < (unsigned)W) colm |= 1u << j;

  // 16-col mask window starting at p2 = 4G-6 (covers 5-wide OR for 12 score cols)
  const int p2 = 4 * G - 6;
  const int pw2 = (p2 < 0) ? 0 : (p2 >> 5);
  const int psh2 = (p2 < 0) ? 0 : (p2 & 31);
  const int pls2 = (p2 < 0) ? -p2 : 0;

  float4 hw[5], cw[5];
  uint32_t snr[5], mor[5], cnb[5];
  constexpr int NK = (PASS == 0) ? 12 : 16;
#pragma unroll
  for (int k = 0; k < NK; ++k) {
    if (PASS != 0) {
      // mask row mr = r0-4+k; horizontal 5-OR (bit i <-> supp col 4G-4+i) +
      // center nibble (cols 4G..4G+3) for the cumulative mask.
      const int mr = r0 - 4 + k;
      uint32_t morrow = 0, cnib = 0;
      if ((unsigned)mr < (unsigned)RROWS) {
        const uint32_t* srow = MIN_ + mr * MW4;
        uint64_t X = (uint64_t)srow[pw2] | ((uint64_t)srow[pw2 + 1] << 32);
        uint64_t win = pls2 ? (X << pls2) : (X >> psh2);
        uint64_t t5 = win | (win >> 1) | (win >> 2) | (win >> 3) | (win >> 4);
        morrow = (uint32_t)t5 & 0xFFFu;
        cnib = (uint32_t)(win >> 6) & 0xFu;
      }
      mor[k % 5] = morrow;
      cnb[k % 5] = cnib;
    }
    const int ks = (PASS == 0) ? k : k - 4;
    if (ks >= 0) {
      // score row sr = r0-2+ks; its 2D supp = OR of mor ring (mask rows sr-2..sr+2)
      const int sr = r0 - 2 + ks;
      uint32_t supp = 0;
      if (PASS != 0) supp = mor[0] | mor[1] | mor[2] | mor[3] | mor[4];
      const float* rowp = S + sr * STR + 4 * G;
      float4 d = ld4(rowp);
      float4 a = (G > 0) ? ld4(rowp - 4) : d;  // garbage-only cols, safe
      float4 e = (G < NG - 1) ? ld4(rowp + 4) : d;
      if (PASS != 0) {
        if (supp & 0x001u) a.x = 0.f;
        if (supp & 0x002u) a.y = 0.f;
        if (supp & 0x004u) a.z = 0.f;
        if (supp & 0x008u) a.w = 0.f;
        if (supp & 0x010u) d.x = 0.f;
        if (supp & 0x020u) d.y = 0.f;
        if (supp & 0x040u) d.z = 0.f;
        if (supp & 0x080u) d.w = 0.f;
        if (supp & 0x100u) e.x = 0.f;
        if (supp & 0x200u) e.y = 0.f;
        if (supp & 0x400u) e.z = 0.f;
        if (supp & 0x800u) e.w = 0.f;
      }
      float4 hm;
      hm.x = max5(a.z, a.w, d.x, d.y, d.z);
      hm.y = max5(a.w, d.x, d.y, d.z, d.w);
      hm.z = max5(d.x, d.y, d.z, d.w, e.x);
      hm.w = max5(d.y, d.z, d.w, e.x, e.y);
      hw[ks % 5] = hm;
      cw[ks % 5] = d;
      snr[ks % 5] = (supp >> 4) & 0xFu;
      if (ks >= 4) {
        const int rq = r0 - 4 + ks;  // emission row
        const int gy = y0 - 12 + rq;
        float4 vm;
        vm.x = max5(hw[0].x, hw[1].x, hw[2].x, hw[3].x, hw[4].x);
        vm.y = max5(hw[0].y, hw[1].y, hw[2].y, hw[3].y, hw[4].y);
        vm.z = max5(hw[0].z, hw[1].z, hw[2].z, hw[3].z, hw[4].z);
        vm.w = max5(hw[0].w, hw[1].w, hw[2].w, hw[3].w, hw[4].w);
        float4 c = cw[(ks + 3) % 5];  // center (masked for PASS 1/2)
        uint32_t nm = (uint32_t)(c.x == vm.x) | ((uint32_t)(c.y == vm.y) << 1) |
                      ((uint32_t)(c.z == vm.z) << 2) | ((uint32_t)(c.w == vm.w) << 3);
        nm &= ((unsigned)gy < (unsigned)H) ? colm : 0u;
        const int widx = rq * MW4 + (G >> 3);
        const int shift = 4 * (G & 7);
        if (PASS == 0) {
          if (nm) atomicOr(&MOUT[widx], nm << shift);
        } else if (PASS == 1) {
          // cumulative mask after iter1: M0 center nibble | (new & ~supp_center)
          uint32_t fin = cnb[ks % 5] | (nm & ~snr[(ks + 3) % 5]);
          if (fin) atomicOr(&MOUT[widx], fin << shift);
        } else {
          uint32_t fin = cnb[ks % 5] | (nm & ~snr[(ks + 3) % 5]);
          if (fin && G >= 3 && G < 19 && rq >= 12 && rq < 76 && gy >= 2 && gy < H - 2) {
#pragma unroll
            for (int j = 0; j < 4; ++j) {
              if ((fin >> j) & 1u) {
                int gx = gx0 + j;
                if (gx >= 2 && gx < W - 2) {
                  float sval = S[rq * STR + 4 * G + j];  // original (unmasked) score
                  if (sval > 0.0f) {
                    uint32_t bits = __float_as_uint(sval);
                    uint32_t flat = (uint32_t)(gy * W + gx);
                    uint64_t key = ((uint64_t)bits << 32) | (uint64_t)(0xFFFFFFFFu - flat);
                    uint32_t pos = atomicAdd(cnt_loc, 1u);
                    if (pos < (uint32_t)LIST_CAP) {
                      list[pos] = key;
                    } else {  // tie overflow: direct global append (rare)
                      uint32_t pp = atomicAdd(&cand_count[b], 1u);
                      if (pp < (uint32_t)CAND_CAP) cand[(size_t)b * CAND_CAP + pp] = key;
                    }
                  }
                }
              }
            }
          }
        }
      }
    }
  }
}

// ---------------- fused 3-pass NMS + candidate emit ----------------------------------
__global__ void __launch_bounds__(256, 4) k_nms(const float* __restrict__ scores,
                                                uint64_t* __restrict__ cand,
                                                uint32_t* __restrict__ cand_count) {
  __shared__ float S[RROWS * STR];
  __shared__ uint32_t M0s[RROWS * MW4];
  __shared__ uint32_t M1s[RROWS * MW4];
  __shared__ uint64_t list[LIST_CAP];
  __shared__ uint32_t cnt_loc, base_g;
  const int b = blockIdx.z;
  const int x0 = blockIdx.x * 64, y0 = blockIdx.y * 64;
  const int tid = threadIdx.x;
  const float* img = scores + (size_t)b * H * W;
  if (tid == 0) cnt_loc = 0;

  for (int u = tid; u < RROWS * NG; u += 256) {
    int r = u / NG, G = u % NG;
    int gy = y0 - 12 + r, gx = x0 - 12 + 4 * G;
    float4 v;
    if ((unsigned)gy < (unsigned)H && (unsigned)gx < (unsigned)W)
      v = ld4(img + (size_t)gy * W + gx);
    else
      v = make_float4(-INFINITY, -INFINITY, -INFINITY, -INFINITY);
    *reinterpret_cast<float4*>(&S[r * STR + 4 * G]) = v;
  }
  for (int i = tid; i < RROWS * MW4; i += 256) {
    M0s[i] = 0;
    M1s[i] = 0;
  }
  __syncthreads();
  if (tid < NUNIT)
    score_pass<0>(tid, x0, y0, S, nullptr, M0s, nullptr, nullptr, nullptr, nullptr, b);
  __syncthreads();
  if (tid < NUNIT)
    score_pass<1>(tid, x0, y0, S, M0s, M1s, nullptr, nullptr, nullptr, nullptr, b);
  __syncthreads();
  if (tid < NUNIT)
    score_pass<2>(tid, x0, y0, S, M1s, nullptr, list, &cnt_loc, cand, cand_count, b);
  __syncthreads();
  uint32_t nblk = cnt_loc;
  uint32_t nmain = nblk < (uint32_t)LIST_CAP ? nblk : (uint32_t)LIST_CAP;
  if (tid == 0) base_g = atomicAdd(&cand_count[b], nmain);
  __syncthreads();
  uint32_t bg = base_g;
  for (uint32_t i = tid; i < nmain; i += 256) {
    uint32_t pp = bg + i;
    if (pp < (uint32_t)CAND_CAP) cand[(size_t)b * CAND_CAP + pp] = list[i];
  }
}

// ---------------- exponent histogram: grid(NHB, B), per-block LDS + sparse merge -----
// Bucket = key>>55 = score_bits>>23 (<= 126 for scores in [0,1)). Per-block LDS
// atomics contend at most slice-deep (~1300); global merge touches only the ~4
// nonzero bins per block (32 atomics/bin/batch — no hot line).
__global__ void __launch_bounds__(256) k_ehist(const uint64_t* __restrict__ cand,
                                               const uint32_t* __restrict__ cand_count,
                                               uint32_t* __restrict__ gehist) {
  __shared__ uint32_t eh[256];
  const int b = blockIdx.y;
  uint32_t n = cand_count[b];
  if (n > (uint32_t)CAND_CAP) n = CAND_CAP;
  eh[threadIdx.x] = 0;
  __syncthreads();
  const uint64_t* cb = cand + (size_t)b * CAND_CAP;
  for (uint32_t i = blockIdx.x * 256 + threadIdx.x; i < n; i += NHB * 256)
    atomicAdd(&eh[(uint32_t)(cb[i] >> 55)], 1u);
  __syncthreads();
  uint32_t v = eh[threadIdx.x];
  if (v) atomicAdd(&gehist[b * 256 + threadIdx.x], v);
}

// ---------------- fine histogram within crossing exponent E --------------------------
// Each block independently recomputes E from gehist (1KB, L2-hit, parallel-redundant)
// then fine-byte histograms keys with exponent E. Merge like k_ehist.
__global__ void __launch_bounds__(256) k_fhist(const uint64_t* __restrict__ cand,
                                               const uint32_t* __restrict__ cand_count,
                                               const uint32_t* __restrict__ gehist,
                                               uint32_t* __restrict__ gfhist) {
  __shared__ uint32_t fh[256];
  __shared__ uint32_t ehl[256];
  __shared__ int sE;
  const int b = blockIdx.y, t = threadIdx.x;
  uint32_t n = cand_count[b];
  if (n > (uint32_t)CAND_CAP) n = CAND_CAP;
  fh[t] = 0;
  ehl[t] = gehist[b * 256 + t];
  __syncthreads();
  if (t == 0) {
    uint32_t run = 0;
    int E = -1;
    for (int e = 255; e >= 0; --e) {
      uint32_t nrun = run + ehl[e];
      if (run < (uint32_t)TOPK && nrun >= (uint32_t)TOPK) E = e;
      run = nrun;
    }
    if (run < (uint32_t)TOPK) E = -1;  // fewer than TOPK candidates: select all
    sE = E;
  }
  __syncthreads();
  const int E = sE;
  if (E < 0) return;
  const uint64_t* cb = cand + (size_t)b * CAND_CAP;
  for (uint32_t i = blockIdx.x * 256 + t; i < n; i += NHB * 256) {
    uint64_t key = cb[i];
    if ((uint32_t)(key >> 55) == (uint32_t)E)
      atomicAdd(&fh[(uint32_t)(key >> 47) & 0xFFu], 1u);
  }
  __syncthreads();
  uint32_t v = fh[t];
  if (v) atomicAdd(&gfhist[b * 256 + t], v);
}

// ---------------- threshold scan (tiny, one block per batch) -------------------------
// thr bucket = (E<<8)|j = score_bits>>15, identical semantics to all passing rounds.
__global__ void __launch_bounds__(256) k_findthr(const uint32_t* __restrict__ gehist,
                                                 const uint32_t* __restrict__ gfhist,
                                                 uint64_t* __restrict__ thr_key) {
  __shared__ uint32_t ehl[256];
  __shared__ uint32_t fhl[256];
  const int b = blockIdx.x, t = threadIdx.x;
  ehl[t] = gehist[b * 256 + t];
  fhl[t] = gfhist[b * 256 + t];
  __syncthreads();
  if (t != 0) return;
  uint32_t run = 0, above = 0;
  int E = -1;
  for (int e = 255; e >= 0; --e) {
    uint32_t nrun = run + ehl[e];
    if (run < (uint32_t)TOPK && nrun >= (uint32_t)TOPK) {
      E = e;
      above = run;
    }
    run = nrun;
  }
  if (run < (uint32_t)TOPK) {
    thr_key[b] = 0ull;  // fewer than TOPK: take all
    return;
  }
  uint32_t r2 = above;
  for (int j = 255; j >= 0; --j) {
    r2 += fhl[j];
    if (r2 >= (uint32_t)TOPK) {
      thr_key[b] = ((uint64_t)(((uint32_t)E << 8) | (uint32_t)j)) << 47;
      return;
    }
  }
}

// ---------------- compact ------------------------------------------------------------
__global__ void __launch_bounds__(1024) k_compact(const uint64_t* __restrict__ cand,
                                                  const uint32_t* __restrict__ cand_count,
                                                  const uint64_t* __restrict__ thr_key,
                                                  uint64_t* __restrict__ sel,
                                                  uint32_t* __restrict__ sel_count) {
  __shared__ uint64_t list[1024];
  __shared__ uint32_t cnt_loc;
  __shared__ uint32_t base_g;
  const int b = blockIdx.y;
  uint32_t n = cand_count[b];
  if (n > (uint32_t)CAND_CAP) n = CAND_CAP;
  const int tid = threadIdx.x;
  if (tid == 0) cnt_loc = 0;
  __syncthreads();
  uint32_t i = blockIdx.x * 1024 + tid;
  if (i < n) {
    uint64_t key = cand[(size_t)b * CAND_CAP + i];
    if (key >= thr_key[b]) {
      uint32_t pos = atomicAdd(&cnt_loc, 1u);
      list[pos] = key;
    }
  }
  __syncthreads();
  uint32_t nblk = cnt_loc;
  if (tid == 0 && nblk > 0) base_g = atomicAdd(&sel_count[b], nblk);
  __syncthreads();
  if (nblk > 0 && (uint32_t)tid < nblk) {
    uint32_t pp = base_g + tid;
    if (pp < (uint32_t)SEL_CAP) sel[(size_t)b * SEL_CAP + pp] = list[tid];
  }
}

// ---------------- full rank + scatter in one kernel ----------------------------------
// rank[me] = #{keys > me} over all n selected keys (keys distinct => permutation =>
// exact JAX top_k order). Chunks looped in-block; final rank scatters directly.
__global__ void __launch_bounds__(256) k_rank(const uint64_t* __restrict__ sel,
                                              const uint32_t* __restrict__ sel_count,
                                              uint64_t* __restrict__ topk) {
  __shared__ uint64_t keys[RK_CH];  // 8 KiB
  const int b = blockIdx.y;
  uint32_t n = sel_count[b];
  if (n > (uint32_t)SEL_CAP) n = SEL_CAP;
  if (blockIdx.x * 256u >= n) return;  // uniform per block
  const uint64_t* sb = sel + (size_t)b * SEL_CAP;
  const uint32_t me = blockIdx.x * 256u + threadIdx.x;
  const uint64_t kme = (me < n) ? sb[me] : 0ull;
  uint32_t rank = 0;
  for (uint32_t c0 = 0; c0 < n; c0 += RK_CH) {
    uint32_t clen = n - c0;
    if (clen > (uint32_t)RK_CH) clen = RK_CH;
    __syncthreads();
    for (uint32_t i = threadIdx.x; i < clen; i += 256) keys[i] = sb[c0 + i];
    __syncthreads();
    uint32_t i = 0;
    for (; i + 8 <= clen; i += 8) {
      rank += (keys[i] > kme);
      rank += (keys[i + 1] > kme);
      rank += (keys[i + 2] > kme);
      rank += (keys[i + 3] > kme);
      rank += (keys[i + 4] > kme);
      rank += (keys[i + 5] > kme);
      rank += (keys[i + 6] > kme);
      rank += (keys[i + 7] > kme);
    }
    for (; i < clen; ++i) rank += (keys[i] > kme);
  }
  if (me < n && rank < (uint32_t)TOPK) topk[(size_t)b * TOPK + rank] = kme;
}

// ---------------- refinement: 8 lanes per keypoint -----------------------------------
__global__ void __launch_bounds__(256) k_refine(const float* __restrict__ scores,
                                                const uint64_t* __restrict__ topk,
                                                float* __restrict__ out) {
  int gid = blockIdx.x * 256 + threadIdx.x;
  int kp = gid >> 3, ln = gid & 7;
  const int b = kp / TOPK;
  const int k = kp % TOPK;
  uint64_t key = topk[(size_t)b * TOPK + k];
  uint32_t flat = 0xFFFFFFFFu - (uint32_t)(key & 0xFFFFFFFFull);
  if (flat >= (uint32_t)(H * W)) flat = 0;  // pad-key guard
  const int ix = (int)(flat % W);
  const int iy = (int)(flat / W);
  const float* img = scores + (size_t)b * H * W;

  const int nt = (ln == 0) ? 4 : 3;
  float v[4];
  float mymax = -INFINITY;
#pragma unroll
  for (int i = 0; i < 4; ++i) {
    if (i < nt) {
      int t = ln + 8 * i;
      int y = iy + t / 5 - 2, x = ix + t % 5 - 2;
      float val = ((unsigned)x < (unsigned)W && (unsigned)y < (unsigned)H)
                      ? img[(size_t)y * W + x] : 0.0f;
      v[i] = val;
      mymax = fmaxf(mymax, val);
    }
  }
#pragma unroll
  for (int m = 1; m < 8; m <<= 1) mymax = fmaxf(mymax, __shfl_xor(mymax, m));
  float e[4];
  float sum = 0.f, sx = 0.f, sy = 0.f;
#pragma unroll
  for (int i = 0; i < 4; ++i) {
    if (i < nt) {
      int t = ln + 8 * i;
      float ev = expf((v[i] - mymax) / 0.1f);
      e[i] = ev;
      sum += ev;
      sx += ev * (float)(t % 5 - 2);
      sy += ev * (float)(t / 5 - 2);
    }
  }
#pragma unroll
  for (int m = 1; m < 8; m <<= 1) {
    sum += __shfl_xor(sum, m);
    sx += __shfl_xor(sx, m);
    sy += __shfl_xor(sy, m);
  }
  float rx = sx / sum, ry = sy / sum;
  float dsp = 0.f;
#pragma unroll
  for (int i = 0; i < 4; ++i) {
    if (i < nt) {
      int t = ln + 8 * i;
      float dx = ((float)(t % 5 - 2) - rx) * 0.5f;
      float dy = ((float)(t / 5 - 2) - ry) * 0.5f;
      dsp += e[i] * (dx * dx + dy * dy);
    }
  }
#pragma unroll
  for (int m = 1; m < 8; m <<= 1) dsp += __shfl_xor(dsp, m);
  if (ln != 0) return;
  dsp /= sum;
  float kx = ((float)ix + rx) / 1023.0f * 2.0f - 1.0f;
  float ky = ((float)iy + ry) / 1023.0f * 2.0f - 1.0f;
  float px = (kx + 1.0f) * 0.5f * 1023.0f;
  float py = (ky + 1.0f) * 0.5f * 1023.0f;
  float x0f = floorf(px), y0f = floorf(py);
  float wx1 = px - x0f, wx0 = 1.0f - wx1;
  float wy1 = py - y0f, wy0 = 1.0f - wy1;
  int x0 = (int)x0f, y0 = (int)y0f;
  float sc = 0.0f;
  {
    int xs[2] = {x0, x0 + 1};
    int ys[2] = {y0, y0 + 1};
    float wxs[2] = {wx0, wx1};
    float wys[2] = {wy0, wy1};
#pragma unroll
    for (int yy = 0; yy < 2; ++yy)
#pragma unroll
      for (int xx = 0; xx < 2; ++xx) {
        int xi = xs[xx], yi = ys[yy];
        bool valid = (xi >= 0 && xi < W && yi >= 0 && yi < H);
        int xc = min(max(xi, 0), W - 1);
        int yc = min(max(yi, 0), H - 1);
        float vv = valid ? img[(size_t)yc * W + xc] : 0.0f;
        sc += vv * (wxs[xx] * wys[yy]);
      }
  }
  out[((size_t)b * TOPK + k) * 2 + 0] = kx;
  out[((size_t)b * TOPK + k) * 2 + 1] = ky;
  out[(size_t)B * TOPK * 2 + (size_t)b * TOPK + k] = sc;
  out[(size_t)B * TOPK * 3 + (size_t)b * TOPK + k] = dsp;
}

}  // namespace

extern "C" void kernel_launch(void* const* d_in, const int* in_sizes, int n_in,
                              void* d_out, int out_size, void* d_ws, size_t ws_size,
                              hipStream_t stream) {
  const float* scores = (const float*)d_in[0];
  float* out = (float*)d_out;
  char* ws = (char*)d_ws;

  uint32_t* cnt = (uint32_t*)(ws + OFF_CNT);
  uint32_t* cand_count = cnt;                    // [B]
  uint32_t* sel_count  = cnt + 8;                // [B]
  uint64_t* thr_key    = (uint64_t*)(cnt + 16);  // [B]
  uint32_t* gehist = (uint32_t*)(ws + OFF_EH);   // [B][256]
  uint32_t* gfhist = (uint32_t*)(ws + OFF_FH);   // [B][256]
  uint64_t* sel  = (uint64_t*)(ws + OFF_SEL);
  uint64_t* topk = (uint64_t*)(ws + OFF_TOPK);
  uint64_t* cand = (uint64_t*)(ws + OFF_CAND);

  hipMemsetAsync(ws + OFF_CNT, 0, MEMSET_BYTES, stream);

  k_nms<<<dim3(W / 64, H / 64, B), 256, 0, stream>>>(scores, cand, cand_count);
  k_ehist<<<dim3(NHB, B), 256, 0, stream>>>(cand, cand_count, gehist);
  k_fhist<<<dim3(NHB, B), 256, 0, stream>>>(cand, cand_count, gehist, gfhist);
  k_findthr<<<B, 256, 0, stream>>>(gehist, gfhist, thr_key);
  k_compact<<<dim3(CAND_CAP / 1024, B), 1024, 0, stream>>>(cand, cand_count, thr_key,
                                                           sel, sel_count);
  k_rank<<<dim3(SEL_CAP / 256, B), 256, 0, stream>>>(sel, sel_count, topk);
  k_refine<<<(B * TOPK * 8) / 256, 256, 0, stream>>>(scores, topk, out);
}

// Round 7
// 208.353 us; speedup vs baseline: 1.6176x; 1.2133x over previous
//
#include <hip/hip_runtime.h>
#include <stdint.h>

// NOTE: identical to the round-6 submission (round-6 bench aborted with a host-side
// core dump and no profile; every component here either passed in round 5 or is a
// byte-identical copy of the verified round-0 baseline's rank/scatter kernels, and
// a full OOB re-audit found nothing — treating the abort as an infra flake and
// re-running the same experiment per the rigor discipline).

namespace {

constexpr int B = 8;
constexpr int H = 1024;
constexpr int W = 1024;
constexpr int TOPK = 4096;
constexpr int CAND_CAP = 131072;  // per batch
constexpr int SEL_CAP = 16384;    // per batch
constexpr int LIST_CAP = 320;     // per 64x64 tile
constexpr int NHB = 32;           // hist slice blocks per batch

// fused-NMS tile: 64x64 interior, radius-12 staged halo.
// Validity chain (3 fused stages): M0 mask valid rows [2,89]/cols [2,86);
// M1 (cumulative after iter1) valid rows [4,87]/cols [4,84); final emission
// valid rows [6,85]/cols [6,82) => interior rows/cols 12..75 fully covered.
constexpr int RROWS = 92;   // staged score rows
constexpr int NG = 22;      // float4 col-groups (88 cols)
constexpr int STR = 88;     // score row stride (floats)
constexpr int MW4 = 4;      // bitpacked mask words per row (96+ bits; word 3 = zero pad)
constexpr int NSTRIP = 11;  // 11 strips x 8 output rows = rows 2..89
constexpr int NUNIT = NG * NSTRIP;  // 242 <= 256

// rank kernel tiling (round-5 lesson: in-block chunk loop = 136 active blocks,
// 7.6% occupancy, 86 us. 2D split over (me, chunk) gives ~680 active blocks.)
constexpr int RK_ME = 256;   // me-keys per block (1/thread)
constexpr int RK_CH = 1024;  // chunk keys staged in LDS per block

// workspace layout (bytes). Threshold = hierarchical exponent/fine-byte histograms,
// grid-parallel (32 blocks/batch) with per-block LDS hists + sparse global merge.
constexpr size_t OFF_CNT   = 0;                                   // 4 KiB
constexpr size_t OFF_EH    = 4096;                                // B*256*4 = 8 KiB
constexpr size_t OFF_FH    = OFF_EH + (size_t)B * 256 * 4;        // 8 KiB
constexpr size_t OFF_RANK  = OFF_FH + (size_t)B * 256 * 4;        // B*SEL_CAP*4 = 512 KiB
constexpr size_t OFF_SEL   = OFF_RANK + (size_t)B * SEL_CAP * 4;  // 1 MiB
constexpr size_t OFF_TOPK  = OFF_SEL + (size_t)B * SEL_CAP * 8;   // 256 KiB
constexpr size_t OFF_CAND  = OFF_TOPK + (size_t)B * TOPK * 8;     // 8 MiB
constexpr size_t MEMSET_BYTES = OFF_SEL;  // cnt + hists + rankg

__device__ __forceinline__ float max5(float a, float b, float c, float d, float e) {
  return fmaxf(fmaxf(fmaxf(a, b), fmaxf(c, d)), e);
}
__device__ __forceinline__ float4 ld4(const float* p) {
  return *reinterpret_cast<const float4*>(p);
}

// One unit: col-group G in [0,22), strip s in [0,11) -> emission rows r0..r0+7
// (r0 = 2+8s). PASS 0: plain local-max -> M0. PASS 1/2: inline dilation of the
// previous mask via a 2-row-lookahead ring (mask rows run 2 ahead of score rows,
// which run 2 ahead of emission). PASS 1 writes cumulative mask M1 = M0|new.
// PASS 2 emits candidates into the LDS list.
template <int PASS>
__device__ __forceinline__ void score_pass(
    int u, int x0, int y0, const float* __restrict__ S,
    const uint32_t* __restrict__ MIN_, uint32_t* __restrict__ MOUT,
    uint64_t* list, uint32_t* cnt_loc, uint64_t* cand, uint32_t* cand_count, int b) {
  const int G = u % NG, s = u / NG;
  const int r0 = 2 + 8 * s;
  const int gx0 = x0 - 12 + 4 * G;
  uint32_t colm = 0;
#pragma unroll
  for (int j = 0; j < 4; ++j)
    if ((unsigned)(gx0 + j) < (unsigned)W) colm |= 1u << j;

  // 16-col mask window starting at p2 = 4G-6 (covers 5-wide OR for 12 score cols)
  const int p2 = 4 * G - 6;
  const int pw2 = (p2 < 0) ? 0 : (p2 >> 5);
  const int psh2 = (p2 < 0) ? 0 : (p2 & 31);
  const int pls2 = (p2 < 0) ? -p2 : 0;

  float4 hw[5], cw[5];
  uint32_t snr[5], mor[5], cnb[5];
  constexpr int NK = (PASS == 0) ? 12 : 16;
#pragma unroll
  for (int k = 0; k < NK; ++k) {
    if (PASS != 0) {
      // mask row mr = r0-4+k; horizontal 5-OR (bit i <-> supp col 4G-4+i) +
      // center nibble (cols 4G..4G+3) for the cumulative mask.
      const int mr = r0 - 4 + k;
      uint32_t morrow = 0, cnib = 0;
      if ((unsigned)mr < (unsigned)RROWS) {
        const uint32_t* srow = MIN_ + mr * MW4;
        uint64_t X = (uint64_t)srow[pw2] | ((uint64_t)srow[pw2 + 1] << 32);
        uint64_t win = pls2 ? (X << pls2) : (X >> psh2);
        uint64_t t5 = win | (win >> 1) | (win >> 2) | (win >> 3) | (win >> 4);
        morrow = (uint32_t)t5 & 0xFFFu;
        cnib = (uint32_t)(win >> 6) & 0xFu;
      }
      mor[k % 5] = morrow;
      cnb[k % 5] = cnib;
    }
    const int ks = (PASS == 0) ? k : k - 4;
    if (ks >= 0) {
      // score row sr = r0-2+ks; its 2D supp = OR of mor ring (mask rows sr-2..sr+2)
      const int sr = r0 - 2 + ks;
      uint32_t supp = 0;
      if (PASS != 0) supp = mor[0] | mor[1] | mor[2] | mor[3] | mor[4];
      const float* rowp = S + sr * STR + 4 * G;
      float4 d = ld4(rowp);
      float4 a = (G > 0) ? ld4(rowp - 4) : d;  // garbage-only cols, safe
      float4 e = (G < NG - 1) ? ld4(rowp + 4) : d;
      if (PASS != 0) {
        if (supp & 0x001u) a.x = 0.f;
        if (supp & 0x002u) a.y = 0.f;
        if (supp & 0x004u) a.z = 0.f;
        if (supp & 0x008u) a.w = 0.f;
        if (supp & 0x010u) d.x = 0.f;
        if (supp & 0x020u) d.y = 0.f;
        if (supp & 0x040u) d.z = 0.f;
        if (supp & 0x080u) d.w = 0.f;
        if (supp & 0x100u) e.x = 0.f;
        if (supp & 0x200u) e.y = 0.f;
        if (supp & 0x400u) e.z = 0.f;
        if (supp & 0x800u) e.w = 0.f;
      }
      float4 hm;
      hm.x = max5(a.z, a.w, d.x, d.y, d.z);
      hm.y = max5(a.w, d.x, d.y, d.z, d.w);
      hm.z = max5(d.x, d.y, d.z, d.w, e.x);
      hm.w = max5(d.y, d.z, d.w, e.x, e.y);
      hw[ks % 5] = hm;
      cw[ks % 5] = d;
      snr[ks % 5] = (supp >> 4) & 0xFu;
      if (ks >= 4) {
        const int rq = r0 - 4 + ks;  // emission row
        const int gy = y0 - 12 + rq;
        float4 vm;
        vm.x = max5(hw[0].x, hw[1].x, hw[2].x, hw[3].x, hw[4].x);
        vm.y = max5(hw[0].y, hw[1].y, hw[2].y, hw[3].y, hw[4].y);
        vm.z = max5(hw[0].z, hw[1].z, hw[2].z, hw[3].z, hw[4].z);
        vm.w = max5(hw[0].w, hw[1].w, hw[2].w, hw[3].w, hw[4].w);
        float4 c = cw[(ks + 3) % 5];  // center (masked for PASS 1/2)
        uint32_t nm = (uint32_t)(c.x == vm.x) | ((uint32_t)(c.y == vm.y) << 1) |
                      ((uint32_t)(c.z == vm.z) << 2) | ((uint32_t)(c.w == vm.w) << 3);
        nm &= ((unsigned)gy < (unsigned)H) ? colm : 0u;
        const int widx = rq * MW4 + (G >> 3);
        const int shift = 4 * (G & 7);
        if (PASS == 0) {
          if (nm) atomicOr(&MOUT[widx], nm << shift);
        } else if (PASS == 1) {
          // cumulative mask after iter1: M0 center nibble | (new & ~supp_center)
          uint32_t fin = cnb[ks % 5] | (nm & ~snr[(ks + 3) % 5]);
          if (fin) atomicOr(&MOUT[widx], fin << shift);
        } else {
          uint32_t fin = cnb[ks % 5] | (nm & ~snr[(ks + 3) % 5]);
          if (fin && G >= 3 && G < 19 && rq >= 12 && rq < 76 && gy >= 2 && gy < H - 2) {
#pragma unroll
            for (int j = 0; j < 4; ++j) {
              if ((fin >> j) & 1u) {
                int gx = gx0 + j;
                if (gx >= 2 && gx < W - 2) {
                  float sval = S[rq * STR + 4 * G + j];  // original (unmasked) score
                  if (sval > 0.0f) {
                    uint32_t bits = __float_as_uint(sval);
                    uint32_t flat = (uint32_t)(gy * W + gx);
                    uint64_t key = ((uint64_t)bits << 32) | (uint64_t)(0xFFFFFFFFu - flat);
                    uint32_t pos = atomicAdd(cnt_loc, 1u);
                    if (pos < (uint32_t)LIST_CAP) {
                      list[pos] = key;
                    } else {  // tie overflow: direct global append (rare)
                      uint32_t pp = atomicAdd(&cand_count[b], 1u);
                      if (pp < (uint32_t)CAND_CAP) cand[(size_t)b * CAND_CAP + pp] = key;
                    }
                  }
                }
              }
            }
          }
        }
      }
    }
  }
}

// ---------------- fused 3-pass NMS + candidate emit ----------------------------------
__global__ void __launch_bounds__(256, 4) k_nms(const float* __restrict__ scores,
                                                uint64_t* __restrict__ cand,
                                                uint32_t* __restrict__ cand_count) {
  __shared__ float S[RROWS * STR];
  __shared__ uint32_t M0s[RROWS * MW4];
  __shared__ uint32_t M1s[RROWS * MW4];
  __shared__ uint64_t list[LIST_CAP];
  __shared__ uint32_t cnt_loc, base_g;
  const int b = blockIdx.z;
  const int x0 = blockIdx.x * 64, y0 = blockIdx.y * 64;
  const int tid = threadIdx.x;
  const float* img = scores + (size_t)b * H * W;
  if (tid == 0) cnt_loc = 0;

  for (int u = tid; u < RROWS * NG; u += 256) {
    int r = u / NG, G = u % NG;
    int gy = y0 - 12 + r, gx = x0 - 12 + 4 * G;
    float4 v;
    if ((unsigned)gy < (unsigned)H && (unsigned)gx < (unsigned)W)
      v = ld4(img + (size_t)gy * W + gx);
    else
      v = make_float4(-INFINITY, -INFINITY, -INFINITY, -INFINITY);
    *reinterpret_cast<float4*>(&S[r * STR + 4 * G]) = v;
  }
  for (int i = tid; i < RROWS * MW4; i += 256) {
    M0s[i] = 0;
    M1s[i] = 0;
  }
  __syncthreads();
  if (tid < NUNIT)
    score_pass<0>(tid, x0, y0, S, nullptr, M0s, nullptr, nullptr, nullptr, nullptr, b);
  __syncthreads();
  if (tid < NUNIT)
    score_pass<1>(tid, x0, y0, S, M0s, M1s, nullptr, nullptr, nullptr, nullptr, b);
  __syncthreads();
  if (tid < NUNIT)
    score_pass<2>(tid, x0, y0, S, M1s, nullptr, list, &cnt_loc, cand, cand_count, b);
  __syncthreads();
  uint32_t nblk = cnt_loc;
  uint32_t nmain = nblk < (uint32_t)LIST_CAP ? nblk : (uint32_t)LIST_CAP;
  if (tid == 0) base_g = atomicAdd(&cand_count[b], nmain);
  __syncthreads();
  uint32_t bg = base_g;
  for (uint32_t i = tid; i < nmain; i += 256) {
    uint32_t pp = bg + i;
    if (pp < (uint32_t)CAND_CAP) cand[(size_t)b * CAND_CAP + pp] = list[i];
  }
}

// ---------------- exponent histogram: grid(NHB, B), per-block LDS + sparse merge -----
// Bucket = key>>55 = score_bits>>23 (<= 126 for scores in [0,1)). Per-block LDS
// atomics contend at most slice-deep (~1300); global merge touches only the ~4
// nonzero bins per block (32 atomics/bin/batch — no hot line).
__global__ void __launch_bounds__(256) k_ehist(const uint64_t* __restrict__ cand,
                                               const uint32_t* __restrict__ cand_count,
                                               uint32_t* __restrict__ gehist) {
  __shared__ uint32_t eh[256];
  const int b = blockIdx.y;
  uint32_t n = cand_count[b];
  if (n > (uint32_t)CAND_CAP) n = CAND_CAP;
  eh[threadIdx.x] = 0;
  __syncthreads();
  const uint64_t* cb = cand + (size_t)b * CAND_CAP;
  for (uint32_t i = blockIdx.x * 256 + threadIdx.x; i < n; i += NHB * 256)
    atomicAdd(&eh[(uint32_t)(cb[i] >> 55)], 1u);
  __syncthreads();
  uint32_t v = eh[threadIdx.x];
  if (v) atomicAdd(&gehist[b * 256 + threadIdx.x], v);
}

// ---------------- fine histogram within crossing exponent E --------------------------
// Each block independently recomputes E from gehist (1KB, L2-hit, parallel-redundant)
// then fine-byte histograms keys with exponent E. Merge like k_ehist.
__global__ void __launch_bounds__(256) k_fhist(const uint64_t* __restrict__ cand,
                                               const uint32_t* __restrict__ cand_count,
                                               const uint32_t* __restrict__ gehist,
                                               uint32_t* __restrict__ gfhist) {
  __shared__ uint32_t fh[256];
  __shared__ uint32_t ehl[256];
  __shared__ int sE;
  const int b = blockIdx.y, t = threadIdx.x;
  uint32_t n = cand_count[b];
  if (n > (uint32_t)CAND_CAP) n = CAND_CAP;
  fh[t] = 0;
  ehl[t] = gehist[b * 256 + t];
  __syncthreads();
  if (t == 0) {
    uint32_t run = 0;
    int E = -1;
    for (int e = 255; e >= 0; --e) {
      uint32_t nrun = run + ehl[e];
      if (run < (uint32_t)TOPK && nrun >= (uint32_t)TOPK) E = e;
      run = nrun;
    }
    if (run < (uint32_t)TOPK) E = -1;  // fewer than TOPK candidates: select all
    sE = E;
  }
  __syncthreads();
  const int E = sE;
  if (E < 0) return;
  const uint64_t* cb = cand + (size_t)b * CAND_CAP;
  for (uint32_t i = blockIdx.x * 256 + t; i < n; i += NHB * 256) {
    uint64_t key = cb[i];
    if ((uint32_t)(key >> 55) == (uint32_t)E)
      atomicAdd(&fh[(uint32_t)(key >> 47) & 0xFFu], 1u);
  }
  __syncthreads();
  uint32_t v = fh[t];
  if (v) atomicAdd(&gfhist[b * 256 + t], v);
}

// ---------------- threshold scan (tiny, one block per batch) -------------------------
// thr bucket = (E<<8)|j = score_bits>>15, identical semantics to all passing rounds.
__global__ void __launch_bounds__(256) k_findthr(const uint32_t* __restrict__ gehist,
                                                 const uint32_t* __restrict__ gfhist,
                                                 uint64_t* __restrict__ thr_key) {
  __shared__ uint32_t ehl[256];
  __shared__ uint32_t fhl[256];
  const int b = blockIdx.x, t = threadIdx.x;
  ehl[t] = gehist[b * 256 + t];
  fhl[t] = gfhist[b * 256 + t];
  __syncthreads();
  if (t != 0) return;
  uint32_t run = 0, above = 0;
  int E = -1;
  for (int e = 255; e >= 0; --e) {
    uint32_t nrun = run + ehl[e];
    if (run < (uint32_t)TOPK && nrun >= (uint32_t)TOPK) {
      E = e;
      above = run;
    }
    run = nrun;
  }
  if (run < (uint32_t)TOPK) {
    thr_key[b] = 0ull;  // fewer than TOPK: take all
    return;
  }
  uint32_t r2 = above;
  for (int j = 255; j >= 0; --j) {
    r2 += fhl[j];
    if (r2 >= (uint32_t)TOPK) {
      thr_key[b] = ((uint64_t)(((uint32_t)E << 8) | (uint32_t)j)) << 47;
      return;
    }
  }
}

// ---------------- compact ------------------------------------------------------------
__global__ void __launch_bounds__(1024) k_compact(const uint64_t* __restrict__ cand,
                                                  const uint32_t* __restrict__ cand_count,
                                                  const uint64_t* __restrict__ thr_key,
                                                  uint64_t* __restrict__ sel,
                                                  uint32_t* __restrict__ sel_count) {
  __shared__ uint64_t list[1024];
  __shared__ uint32_t cnt_loc;
  __shared__ uint32_t base_g;
  const int b = blockIdx.y;
  uint32_t n = cand_count[b];
  if (n > (uint32_t)CAND_CAP) n = CAND_CAP;
  const int tid = threadIdx.x;
  if (tid == 0) cnt_loc = 0;
  __syncthreads();
  uint32_t i = blockIdx.x * 1024 + tid;
  if (i < n) {
    uint64_t key = cand[(size_t)b * CAND_CAP + i];
    if (key >= thr_key[b]) {
      uint32_t pos = atomicAdd(&cnt_loc, 1u);
      list[pos] = key;
    }
  }
  __syncthreads();
  uint32_t nblk = cnt_loc;
  if (tid == 0 && nblk > 0) base_g = atomicAdd(&sel_count[b], nblk);
  __syncthreads();
  if (nblk > 0 && (uint32_t)tid < nblk) {
    uint32_t pp = base_g + tid;
    if (pp < (uint32_t)SEL_CAP) sel[(size_t)b * SEL_CAP + pp] = list[tid];
  }
}

// ---------------- tiled partial ranking ----------------------------------------------
// rank[me] = #{keys > me} over all n selected keys, accumulated per 1024-key chunk
// across grid.y blocks (keys distinct => ranks form a permutation => exact JAX
// top_k order). 2D split keeps ~680 blocks active (vs 136 for in-block chunk loop).
__global__ void __launch_bounds__(RK_ME) k_rank_part(const uint64_t* __restrict__ sel,
                                                     const uint32_t* __restrict__ sel_count,
                                                     uint32_t* __restrict__ rankg) {
  __shared__ uint64_t keys[RK_CH];  // 8 KiB
  const int b = blockIdx.z;
  uint32_t n = sel_count[b];
  if (n > (uint32_t)SEL_CAP) n = SEL_CAP;
  const uint32_t me0 = blockIdx.x * RK_ME;
  const uint32_t c0 = blockIdx.y * RK_CH;
  if (me0 >= n || c0 >= n) return;
  const uint64_t* sb = sel + (size_t)b * SEL_CAP;
  uint32_t clen = n - c0;
  if (clen > (uint32_t)RK_CH) clen = RK_CH;
  for (uint32_t i = threadIdx.x; i < clen; i += RK_ME) keys[i] = sb[c0 + i];
  __syncthreads();
  const uint32_t me = me0 + threadIdx.x;
  if (me >= n) return;
  const uint64_t kme = sb[me];
  uint32_t rank = 0;
  uint32_t i = 0;
  for (; i + 8 <= clen; i += 8) {
    rank += (keys[i] > kme);
    rank += (keys[i + 1] > kme);
    rank += (keys[i + 2] > kme);
    rank += (keys[i + 3] > kme);
    rank += (keys[i + 4] > kme);
    rank += (keys[i + 5] > kme);
    rank += (keys[i + 6] > kme);
    rank += (keys[i + 7] > kme);
  }
  for (; i < clen; ++i) rank += (keys[i] > kme);
  if (rank) atomicAdd(&rankg[(size_t)b * SEL_CAP + me], rank);
}

// scatter: topk[rank[i]] = sel[i] for rank < TOPK
__global__ void __launch_bounds__(256) k_scatter(const uint64_t* __restrict__ sel,
                                                 const uint32_t* __restrict__ sel_count,
                                                 const uint32_t* __restrict__ rankg,
                                                 uint64_t* __restrict__ topk) {
  const int b = blockIdx.y;
  uint32_t n = sel_count[b];
  if (n > (uint32_t)SEL_CAP) n = SEL_CAP;
  uint32_t i = blockIdx.x * 256 + threadIdx.x;
  if (i >= n) return;
  uint32_t r = rankg[(size_t)b * SEL_CAP + i];
  if (r < (uint32_t)TOPK) topk[(size_t)b * TOPK + r] = sel[(size_t)b * SEL_CAP + i];
}

// ---------------- refinement: 8 lanes per keypoint -----------------------------------
__global__ void __launch_bounds__(256) k_refine(const float* __restrict__ scores,
                                                const uint64_t* __restrict__ topk,
                                                float* __restrict__ out) {
  int gid = blockIdx.x * 256 + threadIdx.x;
  int kp = gid >> 3, ln = gid & 7;
  const int b = kp / TOPK;
  const int k = kp % TOPK;
  uint64_t key = topk[(size_t)b * TOPK + k];
  uint32_t flat = 0xFFFFFFFFu - (uint32_t)(key & 0xFFFFFFFFull);
  if (flat >= (uint32_t)(H * W)) flat = 0;  // pad-key guard
  const int ix = (int)(flat % W);
  const int iy = (int)(flat / W);
  const float* img = scores + (size_t)b * H * W;

  const int nt = (ln == 0) ? 4 : 3;
  float v[4];
  float mymax = -INFINITY;
#pragma unroll
  for (int i = 0; i < 4; ++i) {
    if (i < nt) {
      int t = ln + 8 * i;
      int y = iy + t / 5 - 2, x = ix + t % 5 - 2;
      float val = ((unsigned)x < (unsigned)W && (unsigned)y < (unsigned)H)
                      ? img[(size_t)y * W + x] : 0.0f;
      v[i] = val;
      mymax = fmaxf(mymax, val);
    }
  }
#pragma unroll
  for (int m = 1; m < 8; m <<= 1) mymax = fmaxf(mymax, __shfl_xor(mymax, m));
  float e[4];
  float sum = 0.f, sx = 0.f, sy = 0.f;
#pragma unroll
  for (int i = 0; i < 4; ++i) {
    if (i < nt) {
      int t = ln + 8 * i;
      float ev = expf((v[i] - mymax) / 0.1f);
      e[i] = ev;
      sum += ev;
      sx += ev * (float)(t % 5 - 2);
      sy += ev * (float)(t / 5 - 2);
    }
  }
#pragma unroll
  for (int m = 1; m < 8; m <<= 1) {
    sum += __shfl_xor(sum, m);
    sx += __shfl_xor(sx, m);
    sy += __shfl_xor(sy, m);
  }
  float rx = sx / sum, ry = sy / sum;
  float dsp = 0.f;
#pragma unroll
  for (int i = 0; i < 4; ++i) {
    if (i < nt) {
      int t = ln + 8 * i;
      float dx = ((float)(t % 5 - 2) - rx) * 0.5f;
      float dy = ((float)(t / 5 - 2) - ry) * 0.5f;
      dsp += e[i] * (dx * dx + dy * dy);
    }
  }
#pragma unroll
  for (int m = 1; m < 8; m <<= 1) dsp += __shfl_xor(dsp, m);
  if (ln != 0) return;
  dsp /= sum;
  float kx = ((float)ix + rx) / 1023.0f * 2.0f - 1.0f;
  float ky = ((float)iy + ry) / 1023.0f * 2.0f - 1.0f;
  float px = (kx + 1.0f) * 0.5f * 1023.0f;
  float py = (ky + 1.0f) * 0.5f * 1023.0f;
  float x0f = floorf(px), y0f = floorf(py);
  float wx1 = px - x0f, wx0 = 1.0f - wx1;
  float wy1 = py - y0f, wy0 = 1.0f - wy1;
  int x0 = (int)x0f, y0 = (int)y0f;
  float sc = 0.0f;
  {
    int xs[2] = {x0, x0 + 1};
    int ys[2] = {y0, y0 + 1};
    float wxs[2] = {wx0, wx1};
    float wys[2] = {wy0, wy1};
#pragma unroll
    for (int yy = 0; yy < 2; ++yy)
#pragma unroll
      for (int xx = 0; xx < 2; ++xx) {
        int xi = xs[xx], yi = ys[yy];
        bool valid = (xi >= 0 && xi < W && yi >= 0 && yi < H);
        int xc = min(max(xi, 0), W - 1);
        int yc = min(max(yi, 0), H - 1);
        float vv = valid ? img[(size_t)yc * W + xc] : 0.0f;
        sc += vv * (wxs[xx] * wys[yy]);
      }
  }
  out[((size_t)b * TOPK + k) * 2 + 0] = kx;
  out[((size_t)b * TOPK + k) * 2 + 1] = ky;
  out[(size_t)B * TOPK * 2 + (size_t)b * TOPK + k] = sc;
  out[(size_t)B * TOPK * 3 + (size_t)b * TOPK + k] = dsp;
}

}  // namespace

extern "C" void kernel_launch(void* const* d_in, const int* in_sizes, int n_in,
                              void* d_out, int out_size, void* d_ws, size_t ws_size,
                              hipStream_t stream) {
  const float* scores = (const float*)d_in[0];
  float* out = (float*)d_out;
  char* ws = (char*)d_ws;

  uint32_t* cnt = (uint32_t*)(ws + OFF_CNT);
  uint32_t* cand_count = cnt;                    // [B]
  uint32_t* sel_count  = cnt + 8;                // [B]
  uint64_t* thr_key    = (uint64_t*)(cnt + 16);  // [B]
  uint32_t* gehist = (uint32_t*)(ws + OFF_EH);   // [B][256]
  uint32_t* gfhist = (uint32_t*)(ws + OFF_FH);   // [B][256]
  uint32_t* rankg = (uint32_t*)(ws + OFF_RANK);  // [B][SEL_CAP]
  uint64_t* sel  = (uint64_t*)(ws + OFF_SEL);
  uint64_t* topk = (uint64_t*)(ws + OFF_TOPK);
  uint64_t* cand = (uint64_t*)(ws + OFF_CAND);

  hipMemsetAsync(ws + OFF_CNT, 0, MEMSET_BYTES, stream);

  k_nms<<<dim3(W / 64, H / 64, B), 256, 0, stream>>>(scores, cand, cand_count);
  k_ehist<<<dim3(NHB, B), 256, 0, stream>>>(cand, cand_count, gehist);
  k_fhist<<<dim3(NHB, B), 256, 0, stream>>>(cand, cand_count, gehist, gfhist);
  k_findthr<<<B, 256, 0, stream>>>(gehist, gfhist, thr_key);
  k_compact<<<dim3(CAND_CAP / 1024, B), 1024, 0, stream>>>(cand, cand_count, thr_key,
                                                           sel, sel_count);
  k_rank_part<<<dim3(SEL_CAP / RK_ME, SEL_CAP / RK_CH, B), RK_ME, 0, stream>>>(
      sel, sel_count, rankg);
  k_scatter<<<dim3(SEL_CAP / 256, B), 256, 0, stream>>>(sel, sel_count, rankg, topk);
  k_refine<<<(B * TOPK * 8) / 256, 256, 0, stream>>>(scores, topk, out);
}

// Round 8
// 198.689 us; speedup vs baseline: 1.6963x; 1.0486x over previous
//
#include <hip/hip_runtime.h>
#include <stdint.h>

namespace {

constexpr int B = 8;
constexpr int H = 1024;
constexpr int W = 1024;
constexpr int TOPK = 4096;
constexpr int CAND_CAP = 131072;  // per batch
constexpr int SEL_CAP = 16384;    // per batch
constexpr int LIST_CAP = 320;     // per 64x64 tile
constexpr int NHB = 32;           // hist slice blocks per batch

// fused-NMS tile: 64x64 interior, radius-12 staged halo.
// Validity chain (3 fused stages): M0 mask valid rows [2,89]/cols [2,86);
// M1 (cumulative after iter1) valid rows [4,87]/cols [4,84); final emission
// valid rows [6,85]/cols [6,82) => interior rows/cols 12..75 fully covered.
constexpr int RROWS = 92;   // staged score rows
constexpr int NG = 22;      // float4 col-groups (88 cols)
constexpr int STR = 88;     // score row stride (floats)
constexpr int MW = 5;       // bitpacked mask words per row (words 0-2 used, 3-4 zero
                            // pad; stride 5 => cross-strip mask reads land on
                            // different banks: 8 rows * 5 words = 40 ≡ 8 mod 32,
                            // vs MW=4 where 32 ≡ 0 = same-bank conflict)
constexpr int NSTRIP = 11;  // 11 strips x 8 output rows = rows 2..89
constexpr int NUNIT = NG * NSTRIP;  // 242 <= 256

// rank kernel tiling (round-5 lesson: in-block chunk loop = 136 active blocks,
// 7.6% occupancy, 86 us. 2D split over (me, chunk) gives ~680 active blocks.)
constexpr int RK_ME = 256;   // me-keys per block (1/thread)
constexpr int RK_CH = 1024;  // chunk keys staged in LDS per block

// workspace layout (bytes). Threshold = hierarchical exponent/fine-byte histograms,
// grid-parallel (32 blocks/batch) with per-block LDS hists + sparse global merge.
// Round-7 lesson: 9 stream ops cost ~50us in launch overhead — k_findthr folded
// into k_compact, k_scatter folded into k_refine, rankg zeroed by k_compact.
constexpr size_t OFF_CNT   = 0;                                   // 4 KiB
constexpr size_t OFF_EH    = 4096;                                // B*256*4 = 8 KiB
constexpr size_t OFF_FH    = OFF_EH + (size_t)B * 256 * 4;        // 8 KiB
constexpr size_t OFF_RANK  = OFF_FH + (size_t)B * 256 * 4;        // B*SEL_CAP*4 = 512 KiB
constexpr size_t OFF_SEL   = OFF_RANK + (size_t)B * SEL_CAP * 4;  // 1 MiB
constexpr size_t OFF_CAND  = OFF_SEL + (size_t)B * SEL_CAP * 8;   // 8 MiB
constexpr size_t MEMSET_BYTES = OFF_RANK;  // cnt + hist pages only (20.5 KiB)

__device__ __forceinline__ float max5(float a, float b, float c, float d, float e) {
  return fmaxf(fmaxf(fmaxf(a, b), fmaxf(c, d)), e);
}
__device__ __forceinline__ float4 ld4(const float* p) {
  return *reinterpret_cast<const float4*>(p);
}

// One unit: col-group G in [0,22), strip s in [0,11) -> emission rows r0..r0+7
// (r0 = 2+8s). PASS 0: plain local-max -> M0. PASS 1/2: inline dilation of the
// previous mask via a 2-row-lookahead ring (mask rows run 2 ahead of score rows,
// which run 2 ahead of emission). PASS 1 writes cumulative mask M1 = M0|new.
// PASS 2 emits candidates into the LDS list.
template <int PASS>
__device__ __forceinline__ void score_pass(
    int u, int x0, int y0, const float* __restrict__ S,
    const uint32_t* __restrict__ MIN_, uint32_t* __restrict__ MOUT,
    uint64_t* list, uint32_t* cnt_loc, uint64_t* cand, uint32_t* cand_count, int b) {
  const int G = u % NG, s = u / NG;
  const int r0 = 2 + 8 * s;
  const int gx0 = x0 - 12 + 4 * G;
  uint32_t colm = 0;
#pragma unroll
  for (int j = 0; j < 4; ++j)
    if ((unsigned)(gx0 + j) < (unsigned)W) colm |= 1u << j;

  // 16-col mask window starting at p2 = 4G-6 (covers 5-wide OR for 12 score cols)
  const int p2 = 4 * G - 6;
  const int pw2 = (p2 < 0) ? 0 : (p2 >> 5);
  const int psh2 = (p2 < 0) ? 0 : (p2 & 31);
  const int pls2 = (p2 < 0) ? -p2 : 0;

  float4 hw[5], cw[5];
  uint32_t snr[5], mor[5], cnb[5];
  constexpr int NK = (PASS == 0) ? 12 : 16;
#pragma unroll
  for (int k = 0; k < NK; ++k) {
    if (PASS != 0) {
      // mask row mr = r0-4+k; horizontal 5-OR (bit i <-> supp col 4G-4+i) +
      // center nibble (cols 4G..4G+3) for the cumulative mask.
      const int mr = r0 - 4 + k;
      uint32_t morrow = 0, cnib = 0;
      if ((unsigned)mr < (unsigned)RROWS) {
        const uint32_t* srow = MIN_ + mr * MW;
        uint64_t X = (uint64_t)srow[pw2] | ((uint64_t)srow[pw2 + 1] << 32);
        uint64_t win = pls2 ? (X << pls2) : (X >> psh2);
        uint64_t t5 = win | (win >> 1) | (win >> 2) | (win >> 3) | (win >> 4);
        morrow = (uint32_t)t5 & 0xFFFu;
        cnib = (uint32_t)(win >> 6) & 0xFu;
      }
      mor[k % 5] = morrow;
      cnb[k % 5] = cnib;
    }
    const int ks = (PASS == 0) ? k : k - 4;
    if (ks >= 0) {
      // score row sr = r0-2+ks; its 2D supp = OR of mor ring (mask rows sr-2..sr+2)
      const int sr = r0 - 2 + ks;
      uint32_t supp = 0;
      if (PASS != 0) supp = mor[0] | mor[1] | mor[2] | mor[3] | mor[4];
      const float* rowp = S + sr * STR + 4 * G;
      float4 d = ld4(rowp);
      float4 a = (G > 0) ? ld4(rowp - 4) : d;  // garbage-only cols, safe
      float4 e = (G < NG - 1) ? ld4(rowp + 4) : d;
      if (PASS != 0) {
        if (supp & 0x001u) a.x = 0.f;
        if (supp & 0x002u) a.y = 0.f;
        if (supp & 0x004u) a.z = 0.f;
        if (supp & 0x008u) a.w = 0.f;
        if (supp & 0x010u) d.x = 0.f;
        if (supp & 0x020u) d.y = 0.f;
        if (supp & 0x040u) d.z = 0.f;
        if (supp & 0x080u) d.w = 0.f;
        if (supp & 0x100u) e.x = 0.f;
        if (supp & 0x200u) e.y = 0.f;
        if (supp & 0x400u) e.z = 0.f;
        if (supp & 0x800u) e.w = 0.f;
      }
      float4 hm;
      hm.x = max5(a.z, a.w, d.x, d.y, d.z);
      hm.y = max5(a.w, d.x, d.y, d.z, d.w);
      hm.z = max5(d.x, d.y, d.z, d.w, e.x);
      hm.w = max5(d.y, d.z, d.w, e.x, e.y);
      hw[ks % 5] = hm;
      cw[ks % 5] = d;
      snr[ks % 5] = (supp >> 4) & 0xFu;
      if (ks >= 4) {
        const int rq = r0 - 4 + ks;  // emission row
        const int gy = y0 - 12 + rq;
        float4 vm;
        vm.x = max5(hw[0].x, hw[1].x, hw[2].x, hw[3].x, hw[4].x);
        vm.y = max5(hw[0].y, hw[1].y, hw[2].y, hw[3].y, hw[4].y);
        vm.z = max5(hw[0].z, hw[1].z, hw[2].z, hw[3].z, hw[4].z);
        vm.w = max5(hw[0].w, hw[1].w, hw[2].w, hw[3].w, hw[4].w);
        float4 c = cw[(ks + 3) % 5];  // center (masked for PASS 1/2)
        uint32_t nm = (uint32_t)(c.x == vm.x) | ((uint32_t)(c.y == vm.y) << 1) |
                      ((uint32_t)(c.z == vm.z) << 2) | ((uint32_t)(c.w == vm.w) << 3);
        nm &= ((unsigned)gy < (unsigned)H) ? colm : 0u;
        const int widx = rq * MW + (G >> 3);
        const int shift = 4 * (G & 7);
        if (PASS == 0) {
          if (nm) atomicOr(&MOUT[widx], nm << shift);
        } else if (PASS == 1) {
          // cumulative mask after iter1: M0 center nibble | (new & ~supp_center)
          uint32_t fin = cnb[ks % 5] | (nm & ~snr[(ks + 3) % 5]);
          if (fin) atomicOr(&MOUT[widx], fin << shift);
        } else {
          uint32_t fin = cnb[ks % 5] | (nm & ~snr[(ks + 3) % 5]);
          if (fin && G >= 3 && G < 19 && rq >= 12 && rq < 76 && gy >= 2 && gy < H - 2) {
#pragma unroll
            for (int j = 0; j < 4; ++j) {
              if ((fin >> j) & 1u) {
                int gx = gx0 + j;
                if (gx >= 2 && gx < W - 2) {
                  float sval = S[rq * STR + 4 * G + j];  // original (unmasked) score
                  if (sval > 0.0f) {
                    uint32_t bits = __float_as_uint(sval);
                    uint32_t flat = (uint32_t)(gy * W + gx);
                    uint64_t key = ((uint64_t)bits << 32) | (uint64_t)(0xFFFFFFFFu - flat);
                    uint32_t pos = atomicAdd(cnt_loc, 1u);
                    if (pos < (uint32_t)LIST_CAP) {
                      list[pos] = key;
                    } else {  // tie overflow: direct global append (rare)
                      uint32_t pp = atomicAdd(&cand_count[b], 1u);
                      if (pp < (uint32_t)CAND_CAP) cand[(size_t)b * CAND_CAP + pp] = key;
                    }
                  }
                }
              }
            }
          }
        }
      }
    }
  }
}

// ---------------- fused 3-pass NMS + candidate emit ----------------------------------
__global__ void __launch_bounds__(256, 4) k_nms(const float* __restrict__ scores,
                                                uint64_t* __restrict__ cand,
                                                uint32_t* __restrict__ cand_count) {
  __shared__ float S[RROWS * STR];
  __shared__ uint32_t M0s[RROWS * MW];
  __shared__ uint32_t M1s[RROWS * MW];
  __shared__ uint64_t list[LIST_CAP];
  __shared__ uint32_t cnt_loc, base_g;
  const int b = blockIdx.z;
  const int x0 = blockIdx.x * 64, y0 = blockIdx.y * 64;
  const int tid = threadIdx.x;
  const float* img = scores + (size_t)b * H * W;
  if (tid == 0) cnt_loc = 0;

  for (int u = tid; u < RROWS * NG; u += 256) {
    int r = u / NG, G = u % NG;
    int gy = y0 - 12 + r, gx = x0 - 12 + 4 * G;
    float4 v;
    if ((unsigned)gy < (unsigned)H && (unsigned)gx < (unsigned)W)
      v = ld4(img + (size_t)gy * W + gx);
    else
      v = make_float4(-INFINITY, -INFINITY, -INFINITY, -INFINITY);
    *reinterpret_cast<float4*>(&S[r * STR + 4 * G]) = v;
  }
  for (int i = tid; i < RROWS * MW; i += 256) {
    M0s[i] = 0;
    M1s[i] = 0;
  }
  __syncthreads();
  if (tid < NUNIT)
    score_pass<0>(tid, x0, y0, S, nullptr, M0s, nullptr, nullptr, nullptr, nullptr, b);
  __syncthreads();
  if (tid < NUNIT)
    score_pass<1>(tid, x0, y0, S, M0s, M1s, nullptr, nullptr, nullptr, nullptr, b);
  __syncthreads();
  if (tid < NUNIT)
    score_pass<2>(tid, x0, y0, S, M1s, nullptr, list, &cnt_loc, cand, cand_count, b);
  __syncthreads();
  uint32_t nblk = cnt_loc;
  uint32_t nmain = nblk < (uint32_t)LIST_CAP ? nblk : (uint32_t)LIST_CAP;
  if (tid == 0) base_g = atomicAdd(&cand_count[b], nmain);
  __syncthreads();
  uint32_t bg = base_g;
  for (uint32_t i = tid; i < nmain; i += 256) {
    uint32_t pp = bg + i;
    if (pp < (uint32_t)CAND_CAP) cand[(size_t)b * CAND_CAP + pp] = list[i];
  }
}

// ---------------- exponent histogram: grid(NHB, B), per-block LDS + sparse merge -----
// Bucket = key>>55 = score_bits>>23 (<= 126 for scores in [0,1)). Per-block LDS
// atomics contend at most slice-deep (~1300); global merge touches only the ~4
// nonzero bins per block (32 atomics/bin/batch — no hot line).
__global__ void __launch_bounds__(256) k_ehist(const uint64_t* __restrict__ cand,
                                               const uint32_t* __restrict__ cand_count,
                                               uint32_t* __restrict__ gehist) {
  __shared__ uint32_t eh[256];
  const int b = blockIdx.y;
  uint32_t n = cand_count[b];
  if (n > (uint32_t)CAND_CAP) n = CAND_CAP;
  eh[threadIdx.x] = 0;
  __syncthreads();
  const uint64_t* cb = cand + (size_t)b * CAND_CAP;
  for (uint32_t i = blockIdx.x * 256 + threadIdx.x; i < n; i += NHB * 256)
    atomicAdd(&eh[(uint32_t)(cb[i] >> 55)], 1u);
  __syncthreads();
  uint32_t v = eh[threadIdx.x];
  if (v) atomicAdd(&gehist[b * 256 + threadIdx.x], v);
}

// ---------------- fine histogram within crossing exponent E --------------------------
// Each block independently recomputes E from gehist (1KB, L2-hit, parallel-redundant)
// then fine-byte histograms keys with exponent E. Merge like k_ehist.
__global__ void __launch_bounds__(256) k_fhist(const uint64_t* __restrict__ cand,
                                               const uint32_t* __restrict__ cand_count,
                                               const uint32_t* __restrict__ gehist,
                                               uint32_t* __restrict__ gfhist) {
  __shared__ uint32_t fh[256];
  __shared__ uint32_t ehl[256];
  __shared__ int sE;
  const int b = blockIdx.y, t = threadIdx.x;
  uint32_t n = cand_count[b];
  if (n > (uint32_t)CAND_CAP) n = CAND_CAP;
  fh[t] = 0;
  ehl[t] = gehist[b * 256 + t];
  __syncthreads();
  if (t == 0) {
    uint32_t run = 0;
    int E = -1;
    for (int e = 255; e >= 0; --e) {
      uint32_t nrun = run + ehl[e];
      if (run < (uint32_t)TOPK && nrun >= (uint32_t)TOPK) E = e;
      run = nrun;
    }
    if (run < (uint32_t)TOPK) E = -1;  // fewer than TOPK candidates: select all
    sE = E;
  }
  __syncthreads();
  const int E = sE;
  if (E < 0) return;
  const uint64_t* cb = cand + (size_t)b * CAND_CAP;
  for (uint32_t i = blockIdx.x * 256 + t; i < n; i += NHB * 256) {
    uint64_t key = cb[i];
    if ((uint32_t)(key >> 55) == (uint32_t)E)
      atomicAdd(&fh[(uint32_t)(key >> 47) & 0xFFu], 1u);
  }
  __syncthreads();
  uint32_t v = fh[t];
  if (v) atomicAdd(&gfhist[b * 256 + t], v);
}

// ---------------- compact (threshold-find fused in) ----------------------------------
// Each block recomputes thr from gehist/gfhist with a parallel suffix-scan (256-entry
// Hillis-Steele, ~8 barrier steps, redundant across blocks but fully parallel), then
// filters its 1024-candidate slice. Also zeroes rankg[pp] for every sel slot written
// (collectively covers exactly [0,n) — removes the 512 KiB rankg memset).
__global__ void __launch_bounds__(1024) k_compact(const uint64_t* __restrict__ cand,
                                                  const uint32_t* __restrict__ cand_count,
                                                  const uint32_t* __restrict__ gehist,
                                                  const uint32_t* __restrict__ gfhist,
                                                  uint64_t* __restrict__ sel,
                                                  uint32_t* __restrict__ sel_count,
                                                  uint32_t* __restrict__ rankg) {
  __shared__ uint64_t list[1024];
  __shared__ uint32_t cnt_loc, base_g;
  __shared__ uint32_t eh[256], fh[256];
  __shared__ int sE;
  __shared__ uint32_t sAbove;
  __shared__ uint64_t s_thr;
  const int b = blockIdx.y;
  uint32_t n = cand_count[b];
  if (n > (uint32_t)CAND_CAP) n = CAND_CAP;
  const int tid = threadIdx.x;
  if (tid == 0) {
    cnt_loc = 0;
    sE = -1;
    s_thr = 0ull;
  }
  if (tid < 256) {
    eh[tid] = gehist[b * 256 + tid];
    fh[tid] = gfhist[b * 256 + tid];
  }
  __syncthreads();
  // inclusive suffix scans (all threads hit the barriers)
  for (int d = 1; d < 256; d <<= 1) {
    uint32_t ve = 0, vf = 0;
    if (tid < 256) {
      ve = (tid + d < 256) ? eh[tid + d] : 0u;
      vf = (tid + d < 256) ? fh[tid + d] : 0u;
    }
    __syncthreads();
    if (tid < 256) {
      eh[tid] += ve;
      fh[tid] += vf;
    }
    __syncthreads();
  }
  if (tid < 256) {
    uint32_t nxt = (tid < 255) ? eh[tid + 1] : 0u;
    if (eh[tid] >= (uint32_t)TOPK && nxt < (uint32_t)TOPK) {
      sE = tid;
      sAbove = nxt;  // count of keys with exponent > E (< TOPK by construction)
    }
  }
  __syncthreads();
  if (sE >= 0 && tid < 256) {
    uint32_t above = sAbove;
    uint32_t Fn = (tid < 255) ? fh[tid + 1] : 0u;
    if (above + fh[tid] >= (uint32_t)TOPK && above + Fn < (uint32_t)TOPK)
      s_thr = ((uint64_t)(((uint32_t)sE << 8) | (uint32_t)tid)) << 47;
  }
  __syncthreads();
  const uint64_t thr = s_thr;  // 0 => select all (fewer than TOPK candidates)
  uint32_t i = blockIdx.x * 1024 + tid;
  if (i < n) {
    uint64_t key = cand[(size_t)b * CAND_CAP + i];
    if (key >= thr) {
      uint32_t pos = atomicAdd(&cnt_loc, 1u);
      list[pos] = key;
    }
  }
  __syncthreads();
  uint32_t nblk = cnt_loc;
  if (tid == 0 && nblk > 0) base_g = atomicAdd(&sel_count[b], nblk);
  __syncthreads();
  if (nblk > 0 && (uint32_t)tid < nblk) {
    uint32_t pp = base_g + tid;
    if (pp < (uint32_t)SEL_CAP) {
      sel[(size_t)b * SEL_CAP + pp] = list[tid];
      rankg[(size_t)b * SEL_CAP + pp] = 0u;
    }
  }
}

// ---------------- tiled partial ranking ----------------------------------------------
// rank[me] = #{keys > me} over all n selected keys, accumulated per 1024-key chunk
// across grid.y blocks (keys distinct => ranks form a permutation => exact JAX
// top_k order). 2D split keeps ~680 blocks active (vs 136 for in-block chunk loop).
__global__ void __launch_bounds__(RK_ME) k_rank_part(const uint64_t* __restrict__ sel,
                                                     const uint32_t* __restrict__ sel_count,
                                                     uint32_t* __restrict__ rankg) {
  __shared__ uint64_t keys[RK_CH];  // 8 KiB
  const int b = blockIdx.z;
  uint32_t n = sel_count[b];
  if (n > (uint32_t)SEL_CAP) n = SEL_CAP;
  const uint32_t me0 = blockIdx.x * RK_ME;
  const uint32_t c0 = blockIdx.y * RK_CH;
  if (me0 >= n || c0 >= n) return;
  const uint64_t* sb = sel + (size_t)b * SEL_CAP;
  uint32_t clen = n - c0;
  if (clen > (uint32_t)RK_CH) clen = RK_CH;
  for (uint32_t i = threadIdx.x; i < clen; i += RK_ME) keys[i] = sb[c0 + i];
  __syncthreads();
  const uint32_t me = me0 + threadIdx.x;
  if (me >= n) return;
  const uint64_t kme = sb[me];
  uint32_t rank = 0;
  uint32_t i = 0;
  for (; i + 8 <= clen; i += 8) {
    rank += (keys[i] > kme);
    rank += (keys[i + 1] > kme);
    rank += (keys[i + 2] > kme);
    rank += (keys[i + 3] > kme);
    rank += (keys[i + 4] > kme);
    rank += (keys[i + 5] > kme);
    rank += (keys[i + 6] > kme);
    rank += (keys[i + 7] > kme);
  }
  for (; i < clen; ++i) rank += (keys[i] > kme);
  if (rank) atomicAdd(&rankg[(size_t)b * SEL_CAP + me], rank);
}

// ---------------- refinement (scatter fused in): 8 lanes per sel item ----------------
// Iterates over sel indices; lane group reads rank r = rankg[i] and writes outputs
// directly at row r (r < TOPK). Ranks are a permutation, so every output row in
// [0, TOPK) is written exactly once. Removes k_scatter and the topk buffer.
__global__ void __launch_bounds__(256) k_refine(const float* __restrict__ scores,
                                                const uint64_t* __restrict__ sel,
                                                const uint32_t* __restrict__ sel_count,
                                                const uint32_t* __restrict__ rankg,
                                                float* __restrict__ out) {
  int gid = blockIdx.x * 256 + threadIdx.x;
  int idx = gid >> 3, ln = gid & 7;
  const int b = idx / SEL_CAP;
  const int i = idx % SEL_CAP;
  uint32_t n = sel_count[b];
  if (n > (uint32_t)SEL_CAP) n = SEL_CAP;
  if ((uint32_t)i >= n) return;  // uniform across the 8-lane group
  uint32_t r = rankg[(size_t)b * SEL_CAP + i];
  if (r >= (uint32_t)TOPK) return;  // also uniform across the group
  uint64_t key = sel[(size_t)b * SEL_CAP + i];
  uint32_t flat = 0xFFFFFFFFu - (uint32_t)(key & 0xFFFFFFFFull);
  if (flat >= (uint32_t)(H * W)) flat = 0;  // safety guard
  const int ix = (int)(flat % W);
  const int iy = (int)(flat / W);
  const float* img = scores + (size_t)b * H * W;

  const int nt = (ln == 0) ? 4 : 3;
  float v[4];
  float mymax = -INFINITY;
#pragma unroll
  for (int q = 0; q < 4; ++q) {
    if (q < nt) {
      int t = ln + 8 * q;
      int y = iy + t / 5 - 2, x = ix + t % 5 - 2;
      float val = ((unsigned)x < (unsigned)W && (unsigned)y < (unsigned)H)
                      ? img[(size_t)y * W + x] : 0.0f;
      v[q] = val;
      mymax = fmaxf(mymax, val);
    }
  }
#pragma unroll
  for (int m = 1; m < 8; m <<= 1) mymax = fmaxf(mymax, __shfl_xor(mymax, m));
  float e[4];
  float sum = 0.f, sx = 0.f, sy = 0.f;
#pragma unroll
  for (int q = 0; q < 4; ++q) {
    if (q < nt) {
      int t = ln + 8 * q;
      float ev = expf((v[q] - mymax) / 0.1f);
      e[q] = ev;
      sum += ev;
      sx += ev * (float)(t % 5 - 2);
      sy += ev * (float)(t / 5 - 2);
    }
  }
#pragma unroll
  for (int m = 1; m < 8; m <<= 1) {
    sum += __shfl_xor(sum, m);
    sx += __shfl_xor(sx, m);
    sy += __shfl_xor(sy, m);
  }
  float rx = sx / sum, ry = sy / sum;
  float dsp = 0.f;
#pragma unroll
  for (int q = 0; q < 4; ++q) {
    if (q < nt) {
      int t = ln + 8 * q;
      float dx = ((float)(t % 5 - 2) - rx) * 0.5f;
      float dy = ((float)(t / 5 - 2) - ry) * 0.5f;
      dsp += e[q] * (dx * dx + dy * dy);
    }
  }
#pragma unroll
  for (int m = 1; m < 8; m <<= 1) dsp += __shfl_xor(dsp, m);
  if (ln != 0) return;
  dsp /= sum;
  float kx = ((float)ix + rx) / 1023.0f * 2.0f - 1.0f;
  float ky = ((float)iy + ry) / 1023.0f * 2.0f - 1.0f;
  float px = (kx + 1.0f) * 0.5f * 1023.0f;
  float py = (ky + 1.0f) * 0.5f * 1023.0f;
  float x0f = floorf(px), y0f = floorf(py);
  float wx1 = px - x0f, wx0 = 1.0f - wx1;
  float wy1 = py - y0f, wy0 = 1.0f - wy1;
  int x0 = (int)x0f, y0 = (int)y0f;
  float sc = 0.0f;
  {
    int xs[2] = {x0, x0 + 1};
    int ys[2] = {y0, y0 + 1};
    float wxs[2] = {wx0, wx1};
    float wys[2] = {wy0, wy1};
#pragma unroll
    for (int yy = 0; yy < 2; ++yy)
#pragma unroll
      for (int xx = 0; xx < 2; ++xx) {
        int xi = xs[xx], yi = ys[yy];
        bool valid = (xi >= 0 && xi < W && yi >= 0 && yi < H);
        int xc = min(max(xi, 0), W - 1);
        int yc = min(max(yi, 0), H - 1);
        float vv = valid ? img[(size_t)yc * W + xc] : 0.0f;
        sc += vv * (wxs[xx] * wys[yy]);
      }
  }
  out[((size_t)b * TOPK + r) * 2 + 0] = kx;
  out[((size_t)b * TOPK + r) * 2 + 1] = ky;
  out[(size_t)B * TOPK * 2 + (size_t)b * TOPK + r] = sc;
  out[(size_t)B * TOPK * 3 + (size_t)b * TOPK + r] = dsp;
}

}  // namespace

extern "C" void kernel_launch(void* const* d_in, const int* in_sizes, int n_in,
                              void* d_out, int out_size, void* d_ws, size_t ws_size,
                              hipStream_t stream) {
  const float* scores = (const float*)d_in[0];
  float* out = (float*)d_out;
  char* ws = (char*)d_ws;

  uint32_t* cnt = (uint32_t*)(ws + OFF_CNT);
  uint32_t* cand_count = cnt;                    // [B]
  uint32_t* sel_count  = cnt + 8;                // [B]
  uint32_t* gehist = (uint32_t*)(ws + OFF_EH);   // [B][256]
  uint32_t* gfhist = (uint32_t*)(ws + OFF_FH);   // [B][256]
  uint32_t* rankg = (uint32_t*)(ws + OFF_RANK);  // [B][SEL_CAP]
  uint64_t* sel  = (uint64_t*)(ws + OFF_SEL);
  uint64_t* cand = (uint64_t*)(ws + OFF_CAND);

  hipMemsetAsync(ws + OFF_CNT, 0, MEMSET_BYTES, stream);

  k_nms<<<dim3(W / 64, H / 64, B), 256, 0, stream>>>(scores, cand, cand_count);
  k_ehist<<<dim3(NHB, B), 256, 0, stream>>>(cand, cand_count, gehist);
  k_fhist<<<dim3(NHB, B), 256, 0, stream>>>(cand, cand_count, gehist, gfhist);
  k_compact<<<dim3(CAND_CAP / 1024, B), 1024, 0, stream>>>(cand, cand_count, gehist,
                                                           gfhist, sel, sel_count, rankg);
  k_rank_part<<<dim3(SEL_CAP / RK_ME, SEL_CAP / RK_CH, B), RK_ME, 0, stream>>>(
      sel, sel_count, rankg);
  k_refine<<<(B * SEL_CAP * 8) / 256, 256, 0, stream>>>(scores, sel, sel_count, rankg,
                                                        out);
}